// Round 2
// baseline (343.012 us; speedup 1.0000x reference)
//
#include <hip/hip_runtime.h>
#include <math.h>

typedef __bf16  bf16x8 __attribute__((ext_vector_type(8)));
typedef float   f32x4  __attribute__((ext_vector_type(4)));

// async global->LDS, 16B per lane. Pass per-lane dest (= base + lane*16).
#define GLD_LDS16(dst, src)                                                      \
    __builtin_amdgcn_global_load_lds(                                            \
        (const __attribute__((address_space(1))) unsigned int*)(src),            \
        (__attribute__((address_space(3))) unsigned int*)(dst), 16, 0, 0)

// ---------------------------------------------------------------------------
// Kernel T: x[b,ci,h,w] fp32 -> xT[b,h,w,ci] bf16. Also zeroes `pooled`
// (stream-ordered before pool_kernel's atomics; replaces hipMemsetAsync,
// which is a graph-capture risk inside kernel_launch).
// ---------------------------------------------------------------------------
__global__ __launch_bounds__(256) void transpose_kernel(const float* __restrict__ x,
                                                        __bf16* __restrict__ xT,
                                                        float* __restrict__ pooled) {
    if (blockIdx.x == 0 && blockIdx.y == 0) {
        for (int i = threadIdx.x; i < 4096; i += 256) pooled[i] = 0.f;
    }
    int h = blockIdx.x, b = blockIdx.y;
    int lane = threadIdx.x & 63, wv = threadIdx.x >> 6;
#pragma unroll
    for (int i = 0; i < 8; i++) {
        int cq = i * 4 + wv;                       // ci octet 0..31
        const float* src = x + (((size_t)(b * 256 + cq * 8) * 64 + h) * 64 + lane);
        bf16x8 o;
#pragma unroll
        for (int j = 0; j < 8; j++) o[j] = (__bf16)src[(size_t)j * 4096];
        *(bf16x8*)(xT + (((size_t)(b * 64 + h) * 64 + lane) * 256 + cq * 8)) = o;
    }
}

// ---------------------------------------------------------------------------
// Kernel A: global average pool — reads xT (bf16, half the bytes of x,
// LLC-warm from the transpose), fully-coalesced bf16x8 loads.
// Grid: 16 b x 16 hw-slices; LDS reduce across hw-groups; 1 atomic per ci.
// pooled error ~3e-5 vs fp32 path — negligible through sigmoid/softsign.
// ---------------------------------------------------------------------------
__global__ __launch_bounds__(256) void pool_kernel(const __bf16* __restrict__ xT,
                                                   float* __restrict__ pooled) {
    int blk = blockIdx.x;
    int b = blk >> 4, s = blk & 15;
    int t = threadIdx.x;
    int oc  = (t & 31) << 3;     // ci octet base 0..248
    int hw0 = t >> 5;            // 0..7
    float a8[8];
#pragma unroll
    for (int j = 0; j < 8; j++) a8[j] = 0.f;
    const __bf16* base = xT + (((size_t)b * 4096 + s * 256 + hw0) * 256) + oc;
#pragma unroll 4
    for (int i = 0; i < 32; ++i) {
        bf16x8 v = *(const bf16x8*)(base + (size_t)i * 8 * 256);
#pragma unroll
        for (int j = 0; j < 8; j++) a8[j] += (float)v[j];
    }
    __shared__ float red[256][8];
#pragma unroll
    for (int j = 0; j < 8; j++) red[t][j] = a8[j];
    __syncthreads();
    if (t < 32) {
#pragma unroll
        for (int j = 0; j < 8; j++) {
            float s8 = 0.f;
#pragma unroll
            for (int g = 0; g < 8; g++) s8 += red[g * 32 + t][j];
            atomicAdd(&pooled[b * 256 + t * 8 + j], s8 * (1.f / 4096.f));
        }
    }
}

// ---------------------------------------------------------------------------
// Kernel C: routing (computed redundantly per block) + rotated weights.
// rwq[b][tap][co][ci] bf16. One block per co.
// ---------------------------------------------------------------------------
__global__ __launch_bounds__(256) void rotw_kernel(
    const float* __restrict__ weight, const float* __restrict__ pooled,
    const float* __restrict__ w_lambda, const float* __restrict__ w_theta,
    __bf16* __restrict__ rwq) {
    // sl[b][n][p][12-pad] : lambda*R, rows 16B-aligned for float4 reads
    __shared__ __attribute__((aligned(16))) float sl[16][4][9][12];
    __shared__ float wlds[4][2304];      // [n][ci*9+q]
    int co = blockIdx.x;
    int t = threadIdx.x;
#pragma unroll
    for (int n = 0; n < 4; n++) {
        const float* wp = weight + ((size_t)n * 256 + co) * 2304;
        for (int i = t; i < 2304; i += 256) wlds[n][i] = wp[i];
    }
    if (t < 64) {
        int b = t >> 2, n = t & 3;
        float zl = 0.f, zt = 0.f;
        for (int ci = 0; ci < 256; ci++) {
            float p = pooled[b * 256 + ci];
            zl += p * w_lambda[ci * 4 + n];
            zt += p * w_theta[ci * 4 + n];
        }
        float lam = 1.f / (1.f + expf(-zl));
        float th  = 3.14159265358979323846f * (zt / (1.f + fabsf(zt)));
        float xc = cosf(th), ys = sinf(th);
        float a = xc - ys, bb = xc * ys, c = xc + ys;
        float R[9][9];
#pragma unroll
        for (int i = 0; i < 9; i++)
#pragma unroll
            for (int j = 0; j < 9; j++) R[i][j] = 0.f;
        if (th >= 0.f) {
            R[0][0] = a;       R[0][1] = 1 - a;
            R[1][1] = xc - bb; R[1][2] = bb;       R[1][4] = 1 - c + bb; R[1][5] = ys - bb;
            R[2][2] = a;       R[2][5] = 1 - a;
            R[3][0] = bb;      R[3][1] = ys - bb;  R[3][3] = xc - bb;    R[3][4] = 1 - c + bb;
            R[4][4] = 1.f;
            R[5][4] = 1 - c + bb; R[5][5] = xc - bb; R[5][7] = ys - bb;  R[5][8] = bb;
            R[6][3] = 1 - a;   R[6][6] = a;
            R[7][3] = ys - bb; R[7][4] = 1 - c + bb; R[7][6] = bb;       R[7][7] = xc - bb;
            R[8][7] = 1 - a;   R[8][8] = a;
        } else {
            R[0][0] = c;       R[0][3] = 1 - c;
            R[1][0] = -bb;     R[1][1] = xc + bb;  R[1][3] = bb - ys;    R[1][4] = 1 - a - bb;
            R[2][1] = 1 - c;   R[2][2] = c;
            R[3][3] = xc + bb; R[3][4] = 1 - a - bb; R[3][6] = -bb;      R[3][7] = bb - ys;
            R[4][4] = 1.f;
            R[5][1] = bb - ys; R[5][2] = -bb;      R[5][4] = 1 - a - bb; R[5][5] = xc + bb;
            R[6][6] = c;       R[6][7] = 1 - c;
            R[7][4] = 1 - a - bb; R[7][5] = bb - ys; R[7][7] = xc + bb;  R[7][8] = -bb;
            R[8][5] = 1 - c;   R[8][8] = c;
        }
#pragma unroll
        for (int p = 0; p < 9; p++) {
#pragma unroll
            for (int q = 0; q < 9; q++) sl[b][n][p][q] = lam * R[p][q];
            sl[b][n][p][9] = sl[b][n][p][10] = sl[b][n][p][11] = 0.f;
        }
    }
    __syncthreads();
    int ci = t;
    float4 wa[4], wb[4];
    float  wc[4];
#pragma unroll
    for (int n = 0; n < 4; n++) {
        const float* wp = &wlds[n][ci * 9];
        wa[n] = make_float4(wp[0], wp[1], wp[2], wp[3]);
        wb[n] = make_float4(wp[4], wp[5], wp[6], wp[7]);
        wc[n] = wp[8];
    }
    for (int b = 0; b < 16; b++) {
#pragma unroll
        for (int p = 0; p < 9; p++) {
            float s = 0.f;
#pragma unroll
            for (int n = 0; n < 4; n++) {
                float4 sa = *(const float4*)&sl[b][n][p][0];
                float4 sb = *(const float4*)&sl[b][n][p][4];
                float  sc = sl[b][n][p][8];
                s += sa.x * wa[n].x + sa.y * wa[n].y + sa.z * wa[n].z + sa.w * wa[n].w
                   + sb.x * wb[n].x + sb.y * wb[n].y + sb.z * wb[n].z + sb.w * wb[n].w
                   + sc * wc[n];
            }
            rwq[(((size_t)b * 9 + p) * 256 + co) * 256 + ci] = (__bf16)s;
        }
    }
}

// ---------------------------------------------------------------------------
// Kernel D: implicit-GEMM conv + fused BN/ReLU — 2-phase double-buffered.
//   * 512 threads / 8 waves, tile = b x 64co x 16h x 64w, grid 256 = 1 blk/CU.
//   * xs double-buffered (152KB LDS): STAGE(chunk k+1) issued BEFORE compute
//     of chunk k; single syncthreads per chunk drains DMA (T3-minimum recipe).
//   * Weights NOT staged in LDS: A-fragments loaded global->VGPR per tap
//     (rwq is L2-resident via XCD mapping; 8 waves hit same 4KB/tap -> L1).
//     Removes the 4x wave redundancy on weight ds_reads (-33% LDS pipe).
//   * XCD-aware 1D grid: r=lin&7 owns b in {2r,2r+1} -> per-XCD L2 locality.
// ---------------------------------------------------------------------------
#define STAGE_X(bufsel, ci0_)                                                     \
    _Pragma("unroll")                                                             \
    for (int u = wv * 9; u < wv * 9 + 9; ++u) {                                   \
        int rr_ = u >> 2, kq_ = u & 3;                                            \
        int hh_ = h0 - 1 + rr_;                                                   \
        if (hh_ >= 0 && hh_ < 64) {                                               \
            const __bf16* src_ = xT + (((size_t)(b * 64 + hh_) * 64 + lane) * 256 \
                                       + (ci0_) + kq_ * 8);                       \
            GLD_LDS16(&xs[bufsel][rr_][kq_][1 + lane][0], src_);                  \
        } else {                                                                  \
            *(uint4*)&xs[bufsel][rr_][kq_][1 + lane][0] = zero4;                  \
        }                                                                         \
    }

__global__ __launch_bounds__(512) void conv_kernel(
    const __bf16* __restrict__ xT, const __bf16* __restrict__ rwq,
    const float* __restrict__ bn_gamma, const float* __restrict__ bn_beta,
    const float* __restrict__ bn_mean,  const float* __restrict__ bn_var,
    float* __restrict__ out) {
    // [buf][row (16h + 2 halo)][ci-octet][w (64 + 2 halo)][8 ci]
    __shared__ __attribute__((aligned(16))) __bf16 xs[2][18][4][66][8];
    __shared__ float bns[64], bnh[64];

    const int t    = threadIdx.x;
    const int lane = t & 63;
    const int wv   = t >> 6;          // 0..7
    const int l15  = lane & 15;
    const int kq4  = lane >> 4;

    const int lin  = blockIdx.x;
    const int r    = lin & 7;         // XCD class
    const int k    = lin >> 3;        // 0..31
    const int b    = (r << 1) | (k >> 4);
    const int inner = k & 15;
    const int co0  = (inner & 3) << 6;   // 0,64,128,192
    const int h0   = (inner >> 2) << 4;  // 0,16,32,48

    if (t < 64) {
        float inv = rsqrtf(bn_var[co0 + t] + 1e-5f);
        float sc = bn_gamma[co0 + t] * inv;
        bns[t] = sc;
        bnh[t] = bn_beta[co0 + t] - bn_mean[co0 + t] * sc;
    }

    const uint4 zero4 = {0u, 0u, 0u, 0u};
    // zero the w-halo slots of both buffers (never touched by staging)
    if (t < 288) {
        int side = t & 1;
        int kq = (t >> 1) & 3;
        int rem = t >> 3;             // 0..35
        int rr = rem % 18;
        int bf = rem / 18;
        *(uint4*)&xs[bf][rr][kq][side * 65][0] = zero4;
    }

    f32x4 acc[2][4][4];
#pragma unroll
    for (int rr = 0; rr < 2; rr++)
#pragma unroll
        for (int m = 0; m < 4; m++)
#pragma unroll
            for (int n = 0; n < 4; n++) acc[rr][m][n] = (f32x4){0.f, 0.f, 0.f, 0.f};

    STAGE_X(0, 0);
    __syncthreads();                  // drains DMA (compiler emits vmcnt(0))

    for (int c = 0; c < 8; ++c) {
        const int cur = c & 1;
        const int ci0 = c << 5;
        if (c < 7) { STAGE_X(cur ^ 1, ci0 + 32); }   // prefetch next chunk
#pragma unroll
        for (int tap = 0; tap < 9; tap++) {
            const int dh = tap / 3, dw = tap % 3;
            // A-fragments straight from global (L2/L1-resident): 16B/lane
            bf16x8 af[4];
#pragma unroll
            for (int m = 0; m < 4; m++)
                af[m] = *(const bf16x8*)(rwq +
                    ((((size_t)b * 9 + tap) * 256 + co0 + m * 16 + l15) * 256
                     + ci0 + kq4 * 8));
#pragma unroll
            for (int rr = 0; rr < 2; rr++) {
                const int hl = wv * 2 + rr;
#pragma unroll
                for (int nt = 0; nt < 4; nt++) {
                    bf16x8 bfr = *(const bf16x8*)&xs[cur][hl + dh][kq4][nt * 16 + l15 + dw][0];
#pragma unroll
                    for (int m = 0; m < 4; m++)
                        acc[rr][m][nt] = __builtin_amdgcn_mfma_f32_16x16x32_bf16(
                            af[m], bfr, acc[rr][m][nt], 0, 0, 0);
                }
            }
        }
        __syncthreads();              // stage(c+1) landed; compute(c) done
    }

    // epilogue: BN + ReLU. D layout: row(co) = kq4*4+reg, col(w) = l15
#pragma unroll
    for (int rr = 0; rr < 2; rr++) {
        const int h = h0 + wv * 2 + rr;
#pragma unroll
        for (int m = 0; m < 4; m++) {
#pragma unroll
            for (int reg = 0; reg < 4; reg++) {
                int col = m * 16 + kq4 * 4 + reg;        // local co 0..63
                float sc = bns[col], sh = bnh[col];
                int co = co0 + col;
#pragma unroll
                for (int nt = 0; nt < 4; nt++) {
                    int w = nt * 16 + l15;
                    float v = acc[rr][m][nt][reg] * sc + sh;
                    out[(((size_t)b * 256 + co) * 64 + h) * 64 + w] = v > 0.f ? v : 0.f;
                }
            }
        }
    }
}

// ---------------------------------------------------------------------------
extern "C" void kernel_launch(void* const* d_in, const int* in_sizes, int n_in,
                              void* d_out, int out_size, void* d_ws, size_t ws_size,
                              hipStream_t stream) {
    const float* x        = (const float*)d_in[0];
    const float* weight   = (const float*)d_in[1];
    const float* w_lambda = (const float*)d_in[2];
    const float* w_theta  = (const float*)d_in[3];
    const float* bn_gamma = (const float*)d_in[4];
    const float* bn_beta  = (const float*)d_in[5];
    const float* bn_mean  = (const float*)d_in[6];
    const float* bn_var   = (const float*)d_in[7];
    float* out = (float*)d_out;

    char* ws = (char*)d_ws;
    float*  pooled  = (float*)(ws);                     // 4096 f
    __bf16* xT      = (__bf16*)(ws + 49152);            // 33.5 MB
    __bf16* rwq     = (__bf16*)(ws + 49152 + 33554432); // 18.9 MB

    transpose_kernel<<<dim3(64, 16), 256, 0, stream>>>(x, xT, pooled);
    pool_kernel<<<256, 256, 0, stream>>>(xT, pooled);
    rotw_kernel<<<256, 256, 0, stream>>>(weight, pooled, w_lambda, w_theta, rwq);
    conv_kernel<<<256, 512, 0, stream>>>(xT, rwq,
                                         bn_gamma, bn_beta, bn_mean, bn_var, out);
}

// Round 3
// 321.768 us; speedup vs baseline: 1.0660x; 1.0660x over previous
//
#include <hip/hip_runtime.h>
#include <math.h>

typedef __bf16  bf16x8 __attribute__((ext_vector_type(8)));
typedef float   f32x4  __attribute__((ext_vector_type(4)));

// async global->LDS, 16B per lane. Pass per-lane dest (= base + lane*16).
#define GLD_LDS16(dst, src)                                                      \
    __builtin_amdgcn_global_load_lds(                                            \
        (const __attribute__((address_space(1))) unsigned int*)(src),            \
        (__attribute__((address_space(3))) unsigned int*)(dst), 16, 0, 0)

// ---------------------------------------------------------------------------
// Kernel T: x[b,ci,h,w] fp32 -> xT[b,h,w,ci] bf16. Also zeroes `pooled`
// (stream-ordered before pool_kernel's atomics; no hipMemsetAsync in launch).
// ---------------------------------------------------------------------------
__global__ __launch_bounds__(256) void transpose_kernel(const float* __restrict__ x,
                                                        __bf16* __restrict__ xT,
                                                        float* __restrict__ pooled) {
    if (blockIdx.x == 0 && blockIdx.y == 0) {
        for (int i = threadIdx.x; i < 4096; i += 256) pooled[i] = 0.f;
    }
    int h = blockIdx.x, b = blockIdx.y;
    int lane = threadIdx.x & 63, wv = threadIdx.x >> 6;
#pragma unroll
    for (int i = 0; i < 8; i++) {
        int cq = i * 4 + wv;                       // ci octet 0..31
        const float* src = x + (((size_t)(b * 256 + cq * 8) * 64 + h) * 64 + lane);
        bf16x8 o;
#pragma unroll
        for (int j = 0; j < 8; j++) o[j] = (__bf16)src[(size_t)j * 4096];
        *(bf16x8*)(xT + (((size_t)(b * 64 + h) * 64 + lane) * 256 + cq * 8)) = o;
    }
}

// ---------------------------------------------------------------------------
// Kernel A: global average pool — reads xT (bf16, half the bytes of x,
// LLC-warm from the transpose), fully-coalesced bf16x8 loads.
// ---------------------------------------------------------------------------
__global__ __launch_bounds__(256) void pool_kernel(const __bf16* __restrict__ xT,
                                                   float* __restrict__ pooled) {
    int blk = blockIdx.x;
    int b = blk >> 4, s = blk & 15;
    int t = threadIdx.x;
    int oc  = (t & 31) << 3;     // ci octet base 0..248
    int hw0 = t >> 5;            // 0..7
    float a8[8];
#pragma unroll
    for (int j = 0; j < 8; j++) a8[j] = 0.f;
    const __bf16* base = xT + (((size_t)b * 4096 + s * 256 + hw0) * 256) + oc;
#pragma unroll 4
    for (int i = 0; i < 32; ++i) {
        bf16x8 v = *(const bf16x8*)(base + (size_t)i * 8 * 256);
#pragma unroll
        for (int j = 0; j < 8; j++) a8[j] += (float)v[j];
    }
    __shared__ float red[256][8];
#pragma unroll
    for (int j = 0; j < 8; j++) red[t][j] = a8[j];
    __syncthreads();
    if (t < 32) {
#pragma unroll
        for (int j = 0; j < 8; j++) {
            float s8 = 0.f;
#pragma unroll
            for (int g = 0; g < 8; g++) s8 += red[g * 32 + t][j];
            atomicAdd(&pooled[b * 256 + t * 8 + j], s8 * (1.f / 4096.f));
        }
    }
}

// ---------------------------------------------------------------------------
// Kernel C: routing (computed redundantly per block) + rotated weights.
// rwq[b][tap][co][ci] bf16. One block per co.
// ---------------------------------------------------------------------------
__global__ __launch_bounds__(256) void rotw_kernel(
    const float* __restrict__ weight, const float* __restrict__ pooled,
    const float* __restrict__ w_lambda, const float* __restrict__ w_theta,
    __bf16* __restrict__ rwq) {
    // sl[b][n][p][12-pad] : lambda*R, rows 16B-aligned for float4 reads
    __shared__ __attribute__((aligned(16))) float sl[16][4][9][12];
    __shared__ float wlds[4][2304];      // [n][ci*9+q]
    int co = blockIdx.x;
    int t = threadIdx.x;
#pragma unroll
    for (int n = 0; n < 4; n++) {
        const float* wp = weight + ((size_t)n * 256 + co) * 2304;
        for (int i = t; i < 2304; i += 256) wlds[n][i] = wp[i];
    }
    if (t < 64) {
        int b = t >> 2, n = t & 3;
        float zl = 0.f, zt = 0.f;
        for (int ci = 0; ci < 256; ci++) {
            float p = pooled[b * 256 + ci];
            zl += p * w_lambda[ci * 4 + n];
            zt += p * w_theta[ci * 4 + n];
        }
        float lam = 1.f / (1.f + expf(-zl));
        float th  = 3.14159265358979323846f * (zt / (1.f + fabsf(zt)));
        float xc = cosf(th), ys = sinf(th);
        float a = xc - ys, bb = xc * ys, c = xc + ys;
        float R[9][9];
#pragma unroll
        for (int i = 0; i < 9; i++)
#pragma unroll
            for (int j = 0; j < 9; j++) R[i][j] = 0.f;
        if (th >= 0.f) {
            R[0][0] = a;       R[0][1] = 1 - a;
            R[1][1] = xc - bb; R[1][2] = bb;       R[1][4] = 1 - c + bb; R[1][5] = ys - bb;
            R[2][2] = a;       R[2][5] = 1 - a;
            R[3][0] = bb;      R[3][1] = ys - bb;  R[3][3] = xc - bb;    R[3][4] = 1 - c + bb;
            R[4][4] = 1.f;
            R[5][4] = 1 - c + bb; R[5][5] = xc - bb; R[5][7] = ys - bb;  R[5][8] = bb;
            R[6][3] = 1 - a;   R[6][6] = a;
            R[7][3] = ys - bb; R[7][4] = 1 - c + bb; R[7][6] = bb;       R[7][7] = xc - bb;
            R[8][7] = 1 - a;   R[8][8] = a;
        } else {
            R[0][0] = c;       R[0][3] = 1 - c;
            R[1][0] = -bb;     R[1][1] = xc + bb;  R[1][3] = bb - ys;    R[1][4] = 1 - a - bb;
            R[2][1] = 1 - c;   R[2][2] = c;
            R[3][3] = xc + bb; R[3][4] = 1 - a - bb; R[3][6] = -bb;      R[3][7] = bb - ys;
            R[4][4] = 1.f;
            R[5][1] = bb - ys; R[5][2] = -bb;      R[5][4] = 1 - a - bb; R[5][5] = xc + bb;
            R[6][6] = c;       R[6][7] = 1 - c;
            R[7][4] = 1 - a - bb; R[7][5] = bb - ys; R[7][7] = xc + bb;  R[7][8] = -bb;
            R[8][5] = 1 - c;   R[8][8] = c;
        }
#pragma unroll
        for (int p = 0; p < 9; p++) {
#pragma unroll
            for (int q = 0; q < 9; q++) sl[b][n][p][q] = lam * R[p][q];
            sl[b][n][p][9] = sl[b][n][p][10] = sl[b][n][p][11] = 0.f;
        }
    }
    __syncthreads();
    int ci = t;
    float4 wa[4], wb[4];
    float  wc[4];
#pragma unroll
    for (int n = 0; n < 4; n++) {
        const float* wp = &wlds[n][ci * 9];
        wa[n] = make_float4(wp[0], wp[1], wp[2], wp[3]);
        wb[n] = make_float4(wp[4], wp[5], wp[6], wp[7]);
        wc[n] = wp[8];
    }
    for (int b = 0; b < 16; b++) {
#pragma unroll
        for (int p = 0; p < 9; p++) {
            float s = 0.f;
#pragma unroll
            for (int n = 0; n < 4; n++) {
                float4 sa = *(const float4*)&sl[b][n][p][0];
                float4 sb = *(const float4*)&sl[b][n][p][4];
                float  sc = sl[b][n][p][8];
                s += sa.x * wa[n].x + sa.y * wa[n].y + sa.z * wa[n].z + sa.w * wa[n].w
                   + sb.x * wb[n].x + sb.y * wb[n].y + sb.z * wb[n].z + sb.w * wb[n].w
                   + sc * wc[n];
            }
            rwq[(((size_t)b * 9 + p) * 256 + co) * 256 + ci] = (__bf16)s;
        }
    }
}

// ---------------------------------------------------------------------------
// Kernel D: implicit-GEMM conv + fused BN/ReLU.
// R0 memory structure (BOTH x and weights LDS-staged -> FETCH 28.7MB proven)
// + R2 pipeline structure (double-buffered, STAGE(c+1) before compute(c),
// ONE barrier per chunk — no vmcnt(0) drain serialization).
//   * 256 thr / 4 waves, tile = b x 64co x 8h x 64w. LDS 161KB -> 1 blk/CU.
//   * grid 256 = 1 blk/CU; block r=lin&7 (XCD) does b=r then b=r+8
//     sequentially -> per-XCD working set 3.3MB < 4MB L2 at all times.
//   * Floor: MFMA 89K cyc/CU (37us), LDS pipe ~98K cyc (41us).
// ---------------------------------------------------------------------------
#define STAGE_X(bufsel, ci0_)                                                     \
    _Pragma("unroll")                                                             \
    for (int u = wv * 10; u < wv * 10 + 10; ++u) {                                \
        int rr_ = u >> 2, kq_ = u & 3;                                            \
        int hh_ = h0 - 1 + rr_;                                                   \
        if (hh_ >= 0 && hh_ < 64) {                                               \
            const __bf16* src_ = xT + (((size_t)(b * 64 + hh_) * 64 + lane) * 256 \
                                       + (ci0_) + kq_ * 8);                       \
            GLD_LDS16(&xs[bufsel][rr_][kq_][1 + lane][0], src_);                  \
        } else {                                                                  \
            *(uint4*)&xs[bufsel][rr_][kq_][1 + lane][0] = zero4;                  \
        }                                                                         \
    }

#define STAGE_W(bufsel, ci0_)                                                     \
    _Pragma("unroll")                                                             \
    for (int u = wv * 9; u < wv * 9 + 9; ++u) {                                   \
        int tap_ = u >> 2, kq_ = u & 3;                                           \
        const __bf16* src_ = rwq +                                                \
            ((((size_t)b * 9 + tap_) * 256 + co0 + lane) * 256 + (ci0_) + kq_ * 8);\
        GLD_LDS16(&as9[bufsel][tap_][kq_][lane][0], src_);                        \
    }

__global__ __launch_bounds__(256, 1) void conv_kernel(
    const __bf16* __restrict__ xT, const __bf16* __restrict__ rwq,
    const float* __restrict__ bn_gamma, const float* __restrict__ bn_beta,
    const float* __restrict__ bn_mean,  const float* __restrict__ bn_var,
    float* __restrict__ out) {
    // [buf][row (8h + 2 halo)][ci-octet][w (64 + 2 halo)][8 ci]   84,480 B
    __shared__ __attribute__((aligned(16))) __bf16 xs[2][10][4][66][8];
    // [buf][tap][ci-octet][co (64, padded 66 for bank spread)][8 ci] 76,032 B
    __shared__ __attribute__((aligned(16))) __bf16 as9[2][9][4][66][8];
    __shared__ float bns[64], bnh[64];

    const int t    = threadIdx.x;
    const int lane = t & 63;
    const int wv   = t >> 6;          // 0..3
    const int l15  = lane & 15;
    const int kq4  = lane >> 4;

    const int lin   = blockIdx.x;
    const int r     = lin & 7;           // XCD class
    const int inner = lin >> 3;          // 0..31
    const int co0   = (inner & 3) << 6;  // 0,64,128,192
    const int h0    = (inner >> 2) << 3; // 0..56 step 8

    if (t < 64) {
        float inv = rsqrtf(bn_var[co0 + t] + 1e-5f);
        float sc = bn_gamma[co0 + t] * inv;
        bns[t] = sc;
        bnh[t] = bn_beta[co0 + t] - bn_mean[co0 + t] * sc;
    }

    const uint4 zero4 = {0u, 0u, 0u, 0u};
    // zero the w-halo slots of both buffers: 2 buf x 10 rr x 4 kq x 2 sides
    if (t < 160) {
        int side = t & 1;
        int kq = (t >> 1) & 3;
        int rem = t >> 3;             // 0..19
        int rr = rem % 10;
        int bf = rem / 10;
        *(uint4*)&xs[bf][rr][kq][side * 65][0] = zero4;
    }

    for (int bi = 0; bi < 2; ++bi) {
        const int b = r + bi * 8;     // XCD r owns b=r then b=r+8

        f32x4 acc[2][4][4];
#pragma unroll
        for (int rr = 0; rr < 2; rr++)
#pragma unroll
            for (int m = 0; m < 4; m++)
#pragma unroll
                for (int n = 0; n < 4; n++) acc[rr][m][n] = (f32x4){0.f, 0.f, 0.f, 0.f};

        STAGE_X(0, 0);
        STAGE_W(0, 0);
        __syncthreads();              // chunk 0 staged (incl. halo zeros, bns)

#pragma unroll 2
        for (int c = 0; c < 8; ++c) {
            const int cur = c & 1;
            if (c < 7) {              // prefetch next chunk into other buffer
                STAGE_X(cur ^ 1, (c + 1) << 5);
                STAGE_W(cur ^ 1, (c + 1) << 5);
            }
#pragma unroll
            for (int tap = 0; tap < 9; tap++) {
                const int dh = tap / 3, dw = tap % 3;
                bf16x8 af[4];
#pragma unroll
                for (int m = 0; m < 4; m++)
                    af[m] = *(const bf16x8*)&as9[cur][tap][kq4][m * 16 + l15][0];
#pragma unroll
                for (int rr = 0; rr < 2; rr++) {
                    const int hl = wv + rr * 4;
#pragma unroll
                    for (int nt = 0; nt < 4; nt++) {
                        bf16x8 bfr = *(const bf16x8*)&xs[cur][hl + dh][kq4][nt * 16 + l15 + dw][0];
#pragma unroll
                        for (int m = 0; m < 4; m++)
                            acc[rr][m][nt] = __builtin_amdgcn_mfma_f32_16x16x32_bf16(
                                af[m], bfr, acc[rr][m][nt], 0, 0, 0);
                    }
                }
            }
            __syncthreads();          // compute(c) done; stage(c+1) landed
        }

        // epilogue: BN + ReLU. D layout: row(co) = kq4*4+reg, col(w) = l15
#pragma unroll
        for (int rr = 0; rr < 2; rr++) {
            const int h = h0 + wv + rr * 4;
#pragma unroll
            for (int m = 0; m < 4; m++) {
#pragma unroll
                for (int reg = 0; reg < 4; reg++) {
                    int col = m * 16 + kq4 * 4 + reg;        // local co 0..63
                    float sc = bns[col], sh = bnh[col];
                    int co = co0 + col;
#pragma unroll
                    for (int nt = 0; nt < 4; nt++) {
                        int w = nt * 16 + l15;
                        float v = acc[rr][m][nt][reg] * sc + sh;
                        out[(((size_t)b * 256 + co) * 64 + h) * 64 + w] = v > 0.f ? v : 0.f;
                    }
                }
            }
        }
        // next bi: buf0's last reader was compute(c=6), already barriered
    }
}

// ---------------------------------------------------------------------------
extern "C" void kernel_launch(void* const* d_in, const int* in_sizes, int n_in,
                              void* d_out, int out_size, void* d_ws, size_t ws_size,
                              hipStream_t stream) {
    const float* x        = (const float*)d_in[0];
    const float* weight   = (const float*)d_in[1];
    const float* w_lambda = (const float*)d_in[2];
    const float* w_theta  = (const float*)d_in[3];
    const float* bn_gamma = (const float*)d_in[4];
    const float* bn_beta  = (const float*)d_in[5];
    const float* bn_mean  = (const float*)d_in[6];
    const float* bn_var   = (const float*)d_in[7];
    float* out = (float*)d_out;

    char* ws = (char*)d_ws;
    float*  pooled  = (float*)(ws);                     // 4096 f
    __bf16* xT      = (__bf16*)(ws + 49152);            // 33.5 MB
    __bf16* rwq     = (__bf16*)(ws + 49152 + 33554432); // 18.9 MB

    transpose_kernel<<<dim3(64, 16), 256, 0, stream>>>(x, xT, pooled);
    pool_kernel<<<256, 256, 0, stream>>>(xT, pooled);
    rotw_kernel<<<256, 256, 0, stream>>>(weight, pooled, w_lambda, w_theta, rwq);
    conv_kernel<<<256, 256, 0, stream>>>(xT, rwq,
                                         bn_gamma, bn_beta, bn_mean, bn_var, out);
}

// Round 4
// 268.376 us; speedup vs baseline: 1.2781x; 1.1989x over previous
//
#include <hip/hip_runtime.h>
#include <math.h>

typedef __bf16  bf16x8 __attribute__((ext_vector_type(8)));
typedef float   f32x4  __attribute__((ext_vector_type(4)));

// async global->LDS, 16B per lane. Pass per-lane dest (= base + lane*16).
#define GLD_LDS16(dst, src)                                                      \
    __builtin_amdgcn_global_load_lds(                                            \
        (const __attribute__((address_space(1))) unsigned int*)(src),            \
        (__attribute__((address_space(3))) unsigned int*)(dst), 16, 0, 0)

// ---------------------------------------------------------------------------
// Kernel T v2: x[b,ci,h,w] fp32 -> xT[b,h,w,ci] bf16 via LDS transpose.
// Old version wrote 16B at 512B stride (uncoalesced, ~4-8x write amp).
// Now: coalesced float4 reads -> LDS [ci2][w] (bf16 ci-pairs) -> coalesced
// 16B/lane contiguous writes (wave = 8KB contiguous).
// Block = one (b,h): 256ci x 64w. Grid (64,16) -> 4 blocks/CU (LDS 34KB).
// Also zeroes `pooled` (stream-ordered before pool_kernel's atomics).
// ---------------------------------------------------------------------------
__global__ __launch_bounds__(256) void transpose_kernel(const float* __restrict__ x,
                                                        __bf16* __restrict__ xT,
                                                        float* __restrict__ pooled) {
    __shared__ unsigned int lp[128][68];   // [ci-pair][w], pad 64->68 (16B-aligned rows)
    const int h = blockIdx.x, b = blockIdx.y;
    const int t = threadIdx.x;
    if (h == 0 && b == 0) {
        for (int i = t; i < 4096; i += 256) pooled[i] = 0.f;
    }
    // phase L: coalesced reads (16 lanes x 16B = 256B per (ci,h) row segment)
    const int w4 = t & 15;                 // float4 group in w
#pragma unroll
    for (int k = 0; k < 8; ++k) {
        int ci2 = k * 16 + (t >> 4);       // 0..127
        int ci  = ci2 * 2;
        const float4 a = *(const float4*)(x + (((size_t)(b * 256 + ci    ) * 64 + h) * 64 + w4 * 4));
        const float4 c = *(const float4*)(x + (((size_t)(b * 256 + ci + 1) * 64 + h) * 64 + w4 * 4));
        union { __bf16 hh[2]; unsigned int u; } p0, p1, p2, p3;
        p0.hh[0] = (__bf16)a.x; p0.hh[1] = (__bf16)c.x;
        p1.hh[0] = (__bf16)a.y; p1.hh[1] = (__bf16)c.y;
        p2.hh[0] = (__bf16)a.z; p2.hh[1] = (__bf16)c.z;
        p3.hh[0] = (__bf16)a.w; p3.hh[1] = (__bf16)c.w;
        uint4 v = {p0.u, p1.u, p2.u, p3.u};
        *(uint4*)&lp[ci2][w4 * 4] = v;     // b128, 16-lane group contiguous: conflict-free
    }
    __syncthreads();
    // phase S: thread (w, q) writes ci [64q, 64q+64) at fixed w -> 8 x 16B
    const int w = t >> 2, q = t & 3;
    __bf16* dst = xT + (((size_t)b * 64 + h) * 64 + w) * 256 + q * 64;
#pragma unroll
    for (int j = 0; j < 8; ++j) {
        int c0 = q * 32 + j * 4;
        uint4 v;
        v.x = lp[c0 + 0][w];
        v.y = lp[c0 + 1][w];
        v.z = lp[c0 + 2][w];
        v.w = lp[c0 + 3][w];
        *(uint4*)(dst + j * 8) = v;        // wave: 64 lanes = 8KB contiguous
    }
}

// ---------------------------------------------------------------------------
// Kernel A: global average pool — reads xT (bf16, LLC-warm), bf16x8 loads.
// ---------------------------------------------------------------------------
__global__ __launch_bounds__(256) void pool_kernel(const __bf16* __restrict__ xT,
                                                   float* __restrict__ pooled) {
    int blk = blockIdx.x;
    int b = blk >> 4, s = blk & 15;
    int t = threadIdx.x;
    int oc  = (t & 31) << 3;     // ci octet base 0..248
    int hw0 = t >> 5;            // 0..7
    float a8[8];
#pragma unroll
    for (int j = 0; j < 8; j++) a8[j] = 0.f;
    const __bf16* base = xT + (((size_t)b * 4096 + s * 256 + hw0) * 256) + oc;
#pragma unroll 4
    for (int i = 0; i < 32; ++i) {
        bf16x8 v = *(const bf16x8*)(base + (size_t)i * 8 * 256);
#pragma unroll
        for (int j = 0; j < 8; j++) a8[j] += (float)v[j];
    }
    __shared__ float red[256][8];
#pragma unroll
    for (int j = 0; j < 8; j++) red[t][j] = a8[j];
    __syncthreads();
    if (t < 32) {
#pragma unroll
        for (int j = 0; j < 8; j++) {
            float s8 = 0.f;
#pragma unroll
            for (int g = 0; g < 8; g++) s8 += red[g * 32 + t][j];
            atomicAdd(&pooled[b * 256 + t * 8 + j], s8 * (1.f / 4096.f));
        }
    }
}

// ---------------------------------------------------------------------------
// Kernel R: routing, computed ONCE (1 block x 64 threads).
// Writes slg[b][n][p][12-pad] = lambda*R to workspace (27.6KB).
// Replaces 256 blocks x 64 thr x 512 redundant global loads in rotw.
// ---------------------------------------------------------------------------
__global__ __launch_bounds__(64) void routing_kernel(
    const float* __restrict__ pooled, const float* __restrict__ w_lambda,
    const float* __restrict__ w_theta, float* __restrict__ slg) {
    int t = threadIdx.x;          // 0..63
    int b = t >> 2, n = t & 3;
    float zl = 0.f, zt = 0.f;
    for (int ci = 0; ci < 256; ci++) {
        float p = pooled[b * 256 + ci];
        zl += p * w_lambda[ci * 4 + n];
        zt += p * w_theta[ci * 4 + n];
    }
    float lam = 1.f / (1.f + expf(-zl));
    float th  = 3.14159265358979323846f * (zt / (1.f + fabsf(zt)));
    float xc = cosf(th), ys = sinf(th);
    float a = xc - ys, bb = xc * ys, c = xc + ys;
    float R[9][9];
#pragma unroll
    for (int i = 0; i < 9; i++)
#pragma unroll
        for (int j = 0; j < 9; j++) R[i][j] = 0.f;
    if (th >= 0.f) {
        R[0][0] = a;       R[0][1] = 1 - a;
        R[1][1] = xc - bb; R[1][2] = bb;       R[1][4] = 1 - c + bb; R[1][5] = ys - bb;
        R[2][2] = a;       R[2][5] = 1 - a;
        R[3][0] = bb;      R[3][1] = ys - bb;  R[3][3] = xc - bb;    R[3][4] = 1 - c + bb;
        R[4][4] = 1.f;
        R[5][4] = 1 - c + bb; R[5][5] = xc - bb; R[5][7] = ys - bb;  R[5][8] = bb;
        R[6][3] = 1 - a;   R[6][6] = a;
        R[7][3] = ys - bb; R[7][4] = 1 - c + bb; R[7][6] = bb;       R[7][7] = xc - bb;
        R[8][7] = 1 - a;   R[8][8] = a;
    } else {
        R[0][0] = c;       R[0][3] = 1 - c;
        R[1][0] = -bb;     R[1][1] = xc + bb;  R[1][3] = bb - ys;    R[1][4] = 1 - a - bb;
        R[2][1] = 1 - c;   R[2][2] = c;
        R[3][3] = xc + bb; R[3][4] = 1 - a - bb; R[3][6] = -bb;      R[3][7] = bb - ys;
        R[4][4] = 1.f;
        R[5][1] = bb - ys; R[5][2] = -bb;      R[5][4] = 1 - a - bb; R[5][5] = xc + bb;
        R[6][6] = c;       R[6][7] = 1 - c;
        R[7][4] = 1 - a - bb; R[7][5] = bb - ys; R[7][7] = xc + bb;  R[7][8] = -bb;
        R[8][5] = 1 - c;   R[8][8] = c;
    }
    float* o = slg + ((size_t)(b * 4 + n) * 9) * 12;
#pragma unroll
    for (int p = 0; p < 9; p++) {
#pragma unroll
        for (int q = 0; q < 9; q++) o[p * 12 + q] = lam * R[p][q];
        o[p * 12 + 9] = o[p * 12 + 10] = o[p * 12 + 11] = 0.f;
    }
}

// ---------------------------------------------------------------------------
// Kernel C: rotated weights. rwq[b][tap][co][ci] bf16. One block per co.
// Routing now precomputed in slg -> cooperative 27.6KB copy into LDS.
// ---------------------------------------------------------------------------
__global__ __launch_bounds__(256) void rotw_kernel(
    const float* __restrict__ weight, const float* __restrict__ slg,
    __bf16* __restrict__ rwq) {
    __shared__ __attribute__((aligned(16))) float sl[16][4][9][12];
    __shared__ float wlds[4][2304];      // [n][ci*9+q]
    int co = blockIdx.x;
    int t = threadIdx.x;
#pragma unroll
    for (int n = 0; n < 4; n++) {
        const float* wp = weight + ((size_t)n * 256 + co) * 2304;
        for (int i = t; i < 2304; i += 256) wlds[n][i] = wp[i];
    }
    for (int i = t; i < 1728; i += 256)     // 6912 floats = 1728 float4
        ((float4*)sl)[i] = ((const float4*)slg)[i];
    __syncthreads();
    int ci = t;
    float4 wa[4], wb[4];
    float  wc[4];
#pragma unroll
    for (int n = 0; n < 4; n++) {
        const float* wp = &wlds[n][ci * 9];
        wa[n] = make_float4(wp[0], wp[1], wp[2], wp[3]);
        wb[n] = make_float4(wp[4], wp[5], wp[6], wp[7]);
        wc[n] = wp[8];
    }
    for (int b = 0; b < 16; b++) {
#pragma unroll
        for (int p = 0; p < 9; p++) {
            float s = 0.f;
#pragma unroll
            for (int n = 0; n < 4; n++) {
                float4 sa = *(const float4*)&sl[b][n][p][0];
                float4 sb = *(const float4*)&sl[b][n][p][4];
                float  sc = sl[b][n][p][8];
                s += sa.x * wa[n].x + sa.y * wa[n].y + sa.z * wa[n].z + sa.w * wa[n].w
                   + sb.x * wb[n].x + sb.y * wb[n].y + sb.z * wb[n].z + sb.w * wb[n].w
                   + sc * wc[n];
            }
            rwq[(((size_t)b * 9 + p) * 256 + co) * 256 + ci] = (__bf16)s;
        }
    }
}

// ---------------------------------------------------------------------------
// Kernel D: implicit-GEMM conv + fused BN/ReLU — VERBATIM R0 (84.7us proven).
// 2 blocks/CU co-resident (8 waves/CU) provides the overlap; R2/R3 showed
// explicit double-buffering at 1 blk/CU loses the TLP and regresses.
// XCD-aware 1D grid (512): r=lin&7 -> XCD class; class r owns b in {2r,2r+1},
// per-b working set (xT 2.1MB + rwq 1.2MB) stays in that XCD's 4MB L2.
// ---------------------------------------------------------------------------
__global__ __launch_bounds__(256, 2) void conv_kernel(
    const __bf16* __restrict__ xT, const __bf16* __restrict__ rwq,
    const float* __restrict__ bn_gamma, const float* __restrict__ bn_beta,
    const float* __restrict__ bn_mean,  const float* __restrict__ bn_var,
    float* __restrict__ out) {
    __shared__ __attribute__((aligned(16))) __bf16 xs[10][4][66][8];
    __shared__ __attribute__((aligned(16))) __bf16 as9[9][4][66][8];
    __shared__ float bns[64], bnh[64];

    const int t    = threadIdx.x;
    const int lane = t & 63;
    const int wv   = t >> 6;
    const int l15  = lane & 15;
    const int kq4  = lane >> 4;

    const int lin  = blockIdx.x;
    const int r    = lin & 7;
    const int k    = lin >> 3;
    const int b    = (r << 1) | (k >> 5);
    const int inner = k & 31;
    const int co0  = (inner & 3) << 6;
    const int h0   = (inner >> 2) << 3;

    if (t < 64) {
        float inv = rsqrtf(bn_var[co0 + t] + 1e-5f);
        float sc = bn_gamma[co0 + t] * inv;
        bns[t] = sc;
        bnh[t] = bn_beta[co0 + t] - bn_mean[co0 + t] * sc;
    }

    f32x4 acc[2][4][4];
#pragma unroll
    for (int rr = 0; rr < 2; rr++)
#pragma unroll
        for (int m = 0; m < 4; m++)
#pragma unroll
            for (int n = 0; n < 4; n++) acc[rr][m][n] = (f32x4){0.f, 0.f, 0.f, 0.f};

    const uint4 zero4 = {0u, 0u, 0u, 0u};
    if (t < 40) {
        int rr = t >> 2, kq = t & 3;
        *(uint4*)&xs[rr][kq][0][0]  = zero4;
        *(uint4*)&xs[rr][kq][65][0] = zero4;
    }

    for (int ci0 = 0; ci0 < 256; ci0 += 32) {
        __syncthreads();                 // prev chunk's compute done before overwrite
        // stage x: 40 units (rr 0..9, kq 0..3); 10 per wave; lane = w
#pragma unroll
        for (int u = wv * 10; u < wv * 10 + 10; u++) {
            int rr = u >> 2, kq = u & 3;
            int hh = h0 - 1 + rr;
            if (hh >= 0 && hh < 64) {
                const __bf16* src = xT + (((size_t)(b * 64 + hh) * 64 + lane) * 256 + ci0 + kq * 8);
                GLD_LDS16(&xs[rr][kq][1 + lane][0], src);
            } else {
                *(uint4*)&xs[rr][kq][1 + lane][0] = zero4;
            }
        }
        // stage weights, all 9 taps: 36 units (tap, kq); 9 per wave; lane = co
#pragma unroll
        for (int u = wv * 9; u < wv * 9 + 9; u++) {
            int tap = u >> 2, kq = u & 3;
            const __bf16* src = rwq +
                ((((size_t)b * 9 + tap) * 256 + co0 + lane) * 256 + ci0 + kq * 8);
            GLD_LDS16(&as9[tap][kq][lane][0], src);
        }
        __syncthreads();                 // drains DMA; xs + as9 ready
#pragma unroll
        for (int tap = 0; tap < 9; tap++) {
            const int dh = tap / 3, dw = tap % 3;
            bf16x8 af[4];
#pragma unroll
            for (int m = 0; m < 4; m++)
                af[m] = *(const bf16x8*)&as9[tap][kq4][m * 16 + l15][0];
#pragma unroll
            for (int rr = 0; rr < 2; rr++) {
                const int hl = wv + rr * 4;
#pragma unroll
                for (int nt = 0; nt < 4; nt++) {
                    bf16x8 bfr = *(const bf16x8*)&xs[hl + dh][kq4][nt * 16 + l15 + dw][0];
#pragma unroll
                    for (int m = 0; m < 4; m++)
                        acc[rr][m][nt] = __builtin_amdgcn_mfma_f32_16x16x32_bf16(
                            af[m], bfr, acc[rr][m][nt], 0, 0, 0);
                }
            }
        }
    }

    // epilogue: BN + ReLU. D layout: row(co) = kq4*4+reg, col(w) = l15
#pragma unroll
    for (int rr = 0; rr < 2; rr++) {
        const int h = h0 + wv + rr * 4;
#pragma unroll
        for (int m = 0; m < 4; m++) {
#pragma unroll
            for (int reg = 0; reg < 4; reg++) {
                int col = m * 16 + kq4 * 4 + reg;        // local co 0..63
                float sc = bns[col], sh = bnh[col];
                int co = co0 + col;
#pragma unroll
                for (int nt = 0; nt < 4; nt++) {
                    int w = nt * 16 + l15;
                    float v = acc[rr][m][nt][reg] * sc + sh;
                    out[(((size_t)b * 256 + co) * 64 + h) * 64 + w] = v > 0.f ? v : 0.f;
                }
            }
        }
    }
}

// ---------------------------------------------------------------------------
extern "C" void kernel_launch(void* const* d_in, const int* in_sizes, int n_in,
                              void* d_out, int out_size, void* d_ws, size_t ws_size,
                              hipStream_t stream) {
    const float* x        = (const float*)d_in[0];
    const float* weight   = (const float*)d_in[1];
    const float* w_lambda = (const float*)d_in[2];
    const float* w_theta  = (const float*)d_in[3];
    const float* bn_gamma = (const float*)d_in[4];
    const float* bn_beta  = (const float*)d_in[5];
    const float* bn_mean  = (const float*)d_in[6];
    const float* bn_var   = (const float*)d_in[7];
    float* out = (float*)d_out;

    char* ws = (char*)d_ws;
    float*  pooled  = (float*)(ws);                     // 16KB
    float*  slg     = (float*)(ws + 16384);             // 27.6KB (16*4*9*12 f)
    __bf16* xT      = (__bf16*)(ws + 49152);            // 33.5 MB
    __bf16* rwq     = (__bf16*)(ws + 49152 + 33554432); // 18.9 MB

    transpose_kernel<<<dim3(64, 16), 256, 0, stream>>>(x, xT, pooled);
    pool_kernel<<<256, 256, 0, stream>>>(xT, pooled);
    routing_kernel<<<1, 64, 0, stream>>>(pooled, w_lambda, w_theta, slg);
    rotw_kernel<<<256, 256, 0, stream>>>(weight, slg, rwq);
    conv_kernel<<<512, 256, 0, stream>>>(xT, rwq,
                                         bn_gamma, bn_beta, bn_mean, bn_var, out);
}

// Round 5
// 239.908 us; speedup vs baseline: 1.4298x; 1.1187x over previous
//
#include <hip/hip_runtime.h>
#include <math.h>

typedef __bf16  bf16x8 __attribute__((ext_vector_type(8)));
typedef float   f32x4  __attribute__((ext_vector_type(4)));

// async global->LDS, 16B per lane. Pass per-lane dest (= base + lane*16).
#define GLD_LDS16(dst, src)                                                      \
    __builtin_amdgcn_global_load_lds(                                            \
        (const __attribute__((address_space(1))) unsigned int*)(src),            \
        (__attribute__((address_space(3))) unsigned int*)(dst), 16, 0, 0)

// ---------------------------------------------------------------------------
// Kernel T v3: x[b,ci,h,w] fp32 -> xT[b,h,w,ci] bf16 via LDS transpose,
// WITH fused pooling partials (fp32, exact path — better than bf16 re-read).
// Each 16-lane group holds ci2's 64 w-values across its lanes: 4x shfl_xor
// reduce + one float2 store to psum[b][h][ci] (staged in d_out scratch —
// conv overwrites it later; no zero-init, no atomics, no extra workspace).
// Removes pool_kernel entirely (-33.5MB pass, -1 launch).
// ---------------------------------------------------------------------------
__global__ __launch_bounds__(256) void transpose_kernel(const float* __restrict__ x,
                                                        __bf16* __restrict__ xT,
                                                        float* __restrict__ psum) {
    __shared__ unsigned int lp[128][68];   // [ci-pair][w], pad 64->68
    const int h = blockIdx.x, b = blockIdx.y;
    const int t = threadIdx.x;
    const int w4 = t & 15;                 // float4 group in w
    float psA[8], psC[8];
    // phase L: coalesced reads (16 lanes x 16B = 256B per (ci,h) row segment)
#pragma unroll
    for (int k = 0; k < 8; ++k) {
        int ci2 = k * 16 + (t >> 4);       // 0..127
        int ci  = ci2 * 2;
        const float4 a = *(const float4*)(x + (((size_t)(b * 256 + ci    ) * 64 + h) * 64 + w4 * 4));
        const float4 c = *(const float4*)(x + (((size_t)(b * 256 + ci + 1) * 64 + h) * 64 + w4 * 4));
        psA[k] = a.x + a.y + a.z + a.w;
        psC[k] = c.x + c.y + c.z + c.w;
        union { __bf16 hh[2]; unsigned int u; } p0, p1, p2, p3;
        p0.hh[0] = (__bf16)a.x; p0.hh[1] = (__bf16)c.x;
        p1.hh[0] = (__bf16)a.y; p1.hh[1] = (__bf16)c.y;
        p2.hh[0] = (__bf16)a.z; p2.hh[1] = (__bf16)c.z;
        p3.hh[0] = (__bf16)a.w; p3.hh[1] = (__bf16)c.w;
        uint4 v = {p0.u, p1.u, p2.u, p3.u};
        *(uint4*)&lp[ci2][w4 * 4] = v;
    }
    // fused pool partials: reduce across the 16 w4-lanes of each group
#pragma unroll
    for (int k = 0; k < 8; ++k) {
        float sA = psA[k], sC = psC[k];
#pragma unroll
        for (int m = 1; m <= 8; m <<= 1) {
            sA += __shfl_xor(sA, m, 64);
            sC += __shfl_xor(sC, m, 64);
        }
        if (w4 == 0) {
            int ci2 = k * 16 + (t >> 4);
            *(float2*)&psum[(((size_t)b * 64 + h) * 256) + ci2 * 2] =
                make_float2(sA, sC);
        }
    }
    __syncthreads();
    // phase S: thread (w, q) writes ci [64q, 64q+64) at fixed w -> 8 x 16B
    const int w = t >> 2, q = t & 3;
    __bf16* dst = xT + (((size_t)b * 64 + h) * 64 + w) * 256 + q * 64;
#pragma unroll
    for (int j = 0; j < 8; ++j) {
        int c0 = q * 32 + j * 4;
        uint4 v;
        v.x = lp[c0 + 0][w];
        v.y = lp[c0 + 1][w];
        v.z = lp[c0 + 2][w];
        v.w = lp[c0 + 3][w];
        *(uint4*)(dst + j * 8) = v;        // wave: 64 lanes = 8KB contiguous
    }
}

// ---------------------------------------------------------------------------
// Kernel R v2: one block per b (16 blocks x 256 thr).
// 1) pooled_b[ci] = sum_h psum[b][h][ci] / 4096   (coalesced over ci)
// 2) zl/zt[n] via LDS + half-wave shuffle reduce
// 3) 4 threads compute lambda*R -> slg[b][n][p][12]
// ---------------------------------------------------------------------------
__global__ __launch_bounds__(256) void routing_kernel(
    const float* __restrict__ psum, const float* __restrict__ w_lambda,
    const float* __restrict__ w_theta, float* __restrict__ slg) {
    const int b = blockIdx.x, t = threadIdx.x;
    float s = 0.f;
    const float* p = psum + (size_t)b * 16384 + t;
#pragma unroll 8
    for (int h = 0; h < 64; ++h) s += p[h * 256];
    const float pv = s * (1.f / 4096.f);
    __shared__ float red[8][256];
    float4 wl = *(const float4*)&w_lambda[t * 4];
    float4 wt = *(const float4*)&w_theta[t * 4];
    red[0][t] = pv * wl.x; red[1][t] = pv * wl.y;
    red[2][t] = pv * wl.z; red[3][t] = pv * wl.w;
    red[4][t] = pv * wt.x; red[5][t] = pv * wt.y;
    red[6][t] = pv * wt.z; red[7][t] = pv * wt.w;
    __syncthreads();
    __shared__ float zv[8];
    const int rrow = t >> 5, i = t & 31;   // 8 rows x 32 threads
    float acc = red[rrow][i]       + red[rrow][i + 32]
              + red[rrow][i + 64]  + red[rrow][i + 96]
              + red[rrow][i + 128] + red[rrow][i + 160]
              + red[rrow][i + 192] + red[rrow][i + 224];
#pragma unroll
    for (int m = 16; m >= 1; m >>= 1) acc += __shfl_xor(acc, m, 64);
    if (i == 0) zv[rrow] = acc;
    __syncthreads();
    if (t < 4) {
        const int n = t;
        float zl = zv[n], zt = zv[4 + n];
        float lam = 1.f / (1.f + expf(-zl));
        float th  = 3.14159265358979323846f * (zt / (1.f + fabsf(zt)));
        float xc = cosf(th), ys = sinf(th);
        float a = xc - ys, bb = xc * ys, c = xc + ys;
        float R[9][9];
#pragma unroll
        for (int ii = 0; ii < 9; ii++)
#pragma unroll
            for (int jj = 0; jj < 9; jj++) R[ii][jj] = 0.f;
        if (th >= 0.f) {
            R[0][0] = a;       R[0][1] = 1 - a;
            R[1][1] = xc - bb; R[1][2] = bb;       R[1][4] = 1 - c + bb; R[1][5] = ys - bb;
            R[2][2] = a;       R[2][5] = 1 - a;
            R[3][0] = bb;      R[3][1] = ys - bb;  R[3][3] = xc - bb;    R[3][4] = 1 - c + bb;
            R[4][4] = 1.f;
            R[5][4] = 1 - c + bb; R[5][5] = xc - bb; R[5][7] = ys - bb;  R[5][8] = bb;
            R[6][3] = 1 - a;   R[6][6] = a;
            R[7][3] = ys - bb; R[7][4] = 1 - c + bb; R[7][6] = bb;       R[7][7] = xc - bb;
            R[8][7] = 1 - a;   R[8][8] = a;
        } else {
            R[0][0] = c;       R[0][3] = 1 - c;
            R[1][0] = -bb;     R[1][1] = xc + bb;  R[1][3] = bb - ys;    R[1][4] = 1 - a - bb;
            R[2][1] = 1 - c;   R[2][2] = c;
            R[3][3] = xc + bb; R[3][4] = 1 - a - bb; R[3][6] = -bb;      R[3][7] = bb - ys;
            R[4][4] = 1.f;
            R[5][1] = bb - ys; R[5][2] = -bb;      R[5][4] = 1 - a - bb; R[5][5] = xc + bb;
            R[6][6] = c;       R[6][7] = 1 - c;
            R[7][4] = 1 - a - bb; R[7][5] = bb - ys; R[7][7] = xc + bb;  R[7][8] = -bb;
            R[8][5] = 1 - c;   R[8][8] = c;
        }
        float* o = slg + ((size_t)(b * 4 + n) * 9) * 12;
#pragma unroll
        for (int pp = 0; pp < 9; pp++) {
#pragma unroll
            for (int q = 0; q < 9; q++) o[pp * 12 + q] = lam * R[pp][q];
            o[pp * 12 + 9] = o[pp * 12 + 10] = o[pp * 12 + 11] = 0.f;
        }
    }
}

// ---------------------------------------------------------------------------
// Kernel C: rotated weights. rwq[b][tap][co][ci] bf16. One block per co.
// Weights read DIRECT from global (the old LDS stage had zero reuse —
// each float was read exactly once); slg copied to LDS (reused 256x).
// ---------------------------------------------------------------------------
__global__ __launch_bounds__(256) void rotw_kernel(
    const float* __restrict__ weight, const float* __restrict__ slg,
    __bf16* __restrict__ rwq) {
    __shared__ __attribute__((aligned(16))) float sl[16][4][9][12];
    int co = blockIdx.x;
    int t = threadIdx.x;
    for (int i = t; i < 1728; i += 256)     // 6912 floats = 1728 float4
        ((float4*)sl)[i] = ((const float4*)slg)[i];
    int ci = t;
    float4 wa[4], wb[4];
    float  wc[4];
#pragma unroll
    for (int n = 0; n < 4; n++) {
        const float* wp = weight + ((size_t)n * 256 + co) * 2304 + (size_t)ci * 9;
        wa[n] = make_float4(wp[0], wp[1], wp[2], wp[3]);
        wb[n] = make_float4(wp[4], wp[5], wp[6], wp[7]);
        wc[n] = wp[8];
    }
    __syncthreads();
    for (int b = 0; b < 16; b++) {
#pragma unroll
        for (int p = 0; p < 9; p++) {
            float s = 0.f;
#pragma unroll
            for (int n = 0; n < 4; n++) {
                float4 sa = *(const float4*)&sl[b][n][p][0];
                float4 sb = *(const float4*)&sl[b][n][p][4];
                float  sc = sl[b][n][p][8];
                s += sa.x * wa[n].x + sa.y * wa[n].y + sa.z * wa[n].z + sa.w * wa[n].w
                   + sb.x * wb[n].x + sb.y * wb[n].y + sb.z * wb[n].z + sb.w * wb[n].w
                   + sc * wc[n];
            }
            rwq[(((size_t)b * 9 + p) * 256 + co) * 256 + ci] = (__bf16)s;
        }
    }
}

// ---------------------------------------------------------------------------
// Kernel D: implicit-GEMM conv + fused BN/ReLU — VERBATIM R0 (83.5us proven).
// 2 blocks/CU co-resident (8 waves/CU) provides the overlap; R2/R3 showed
// explicit double-buffering at 1 blk/CU loses the TLP and regresses.
// ---------------------------------------------------------------------------
__global__ __launch_bounds__(256, 2) void conv_kernel(
    const __bf16* __restrict__ xT, const __bf16* __restrict__ rwq,
    const float* __restrict__ bn_gamma, const float* __restrict__ bn_beta,
    const float* __restrict__ bn_mean,  const float* __restrict__ bn_var,
    float* __restrict__ out) {
    __shared__ __attribute__((aligned(16))) __bf16 xs[10][4][66][8];
    __shared__ __attribute__((aligned(16))) __bf16 as9[9][4][66][8];
    __shared__ float bns[64], bnh[64];

    const int t    = threadIdx.x;
    const int lane = t & 63;
    const int wv   = t >> 6;
    const int l15  = lane & 15;
    const int kq4  = lane >> 4;

    const int lin  = blockIdx.x;
    const int r    = lin & 7;
    const int k    = lin >> 3;
    const int b    = (r << 1) | (k >> 5);
    const int inner = k & 31;
    const int co0  = (inner & 3) << 6;
    const int h0   = (inner >> 2) << 3;

    if (t < 64) {
        float inv = rsqrtf(bn_var[co0 + t] + 1e-5f);
        float sc = bn_gamma[co0 + t] * inv;
        bns[t] = sc;
        bnh[t] = bn_beta[co0 + t] - bn_mean[co0 + t] * sc;
    }

    f32x4 acc[2][4][4];
#pragma unroll
    for (int rr = 0; rr < 2; rr++)
#pragma unroll
        for (int m = 0; m < 4; m++)
#pragma unroll
            for (int n = 0; n < 4; n++) acc[rr][m][n] = (f32x4){0.f, 0.f, 0.f, 0.f};

    const uint4 zero4 = {0u, 0u, 0u, 0u};
    if (t < 40) {
        int rr = t >> 2, kq = t & 3;
        *(uint4*)&xs[rr][kq][0][0]  = zero4;
        *(uint4*)&xs[rr][kq][65][0] = zero4;
    }

    for (int ci0 = 0; ci0 < 256; ci0 += 32) {
        __syncthreads();                 // prev chunk's compute done before overwrite
#pragma unroll
        for (int u = wv * 10; u < wv * 10 + 10; u++) {
            int rr = u >> 2, kq = u & 3;
            int hh = h0 - 1 + rr;
            if (hh >= 0 && hh < 64) {
                const __bf16* src = xT + (((size_t)(b * 64 + hh) * 64 + lane) * 256 + ci0 + kq * 8);
                GLD_LDS16(&xs[rr][kq][1 + lane][0], src);
            } else {
                *(uint4*)&xs[rr][kq][1 + lane][0] = zero4;
            }
        }
#pragma unroll
        for (int u = wv * 9; u < wv * 9 + 9; u++) {
            int tap = u >> 2, kq = u & 3;
            const __bf16* src = rwq +
                ((((size_t)b * 9 + tap) * 256 + co0 + lane) * 256 + ci0 + kq * 8);
            GLD_LDS16(&as9[tap][kq][lane][0], src);
        }
        __syncthreads();                 // drains DMA; xs + as9 ready
#pragma unroll
        for (int tap = 0; tap < 9; tap++) {
            const int dh = tap / 3, dw = tap % 3;
            bf16x8 af[4];
#pragma unroll
            for (int m = 0; m < 4; m++)
                af[m] = *(const bf16x8*)&as9[tap][kq4][m * 16 + l15][0];
#pragma unroll
            for (int rr = 0; rr < 2; rr++) {
                const int hl = wv + rr * 4;
#pragma unroll
                for (int nt = 0; nt < 4; nt++) {
                    bf16x8 bfr = *(const bf16x8*)&xs[hl + dh][kq4][nt * 16 + l15 + dw][0];
#pragma unroll
                    for (int m = 0; m < 4; m++)
                        acc[rr][m][nt] = __builtin_amdgcn_mfma_f32_16x16x32_bf16(
                            af[m], bfr, acc[rr][m][nt], 0, 0, 0);
                }
            }
        }
    }

    // epilogue: BN + ReLU. D layout: row(co) = kq4*4+reg, col(w) = l15
#pragma unroll
    for (int rr = 0; rr < 2; rr++) {
        const int h = h0 + wv + rr * 4;
#pragma unroll
        for (int m = 0; m < 4; m++) {
#pragma unroll
            for (int reg = 0; reg < 4; reg++) {
                int col = m * 16 + kq4 * 4 + reg;        // local co 0..63
                float sc = bns[col], sh = bnh[col];
                int co = co0 + col;
#pragma unroll
                for (int nt = 0; nt < 4; nt++) {
                    int w = nt * 16 + l15;
                    float v = acc[rr][m][nt][reg] * sc + sh;
                    out[(((size_t)b * 256 + co) * 64 + h) * 64 + w] = v > 0.f ? v : 0.f;
                }
            }
        }
    }
}

// ---------------------------------------------------------------------------
extern "C" void kernel_launch(void* const* d_in, const int* in_sizes, int n_in,
                              void* d_out, int out_size, void* d_ws, size_t ws_size,
                              hipStream_t stream) {
    const float* x        = (const float*)d_in[0];
    const float* weight   = (const float*)d_in[1];
    const float* w_lambda = (const float*)d_in[2];
    const float* w_theta  = (const float*)d_in[3];
    const float* bn_gamma = (const float*)d_in[4];
    const float* bn_beta  = (const float*)d_in[5];
    const float* bn_mean  = (const float*)d_in[6];
    const float* bn_var   = (const float*)d_in[7];
    float* out = (float*)d_out;

    char* ws = (char*)d_ws;
    float*  slg     = (float*)(ws + 16384);             // 27.6KB (16*4*9*12 f)
    __bf16* xT      = (__bf16*)(ws + 49152);            // 33.5 MB
    __bf16* rwq     = (__bf16*)(ws + 49152 + 33554432); // 18.9 MB
    float*  psum    = out;   // 4MB scratch in d_out; conv overwrites it later

    transpose_kernel<<<dim3(64, 16), 256, 0, stream>>>(x, xT, psum);
    routing_kernel<<<16, 256, 0, stream>>>(psum, w_lambda, w_theta, slg);
    rotw_kernel<<<256, 256, 0, stream>>>(weight, slg, rwq);
    conv_kernel<<<512, 256, 0, stream>>>(xT, rwq,
                                         bn_gamma, bn_beta, bn_mean, bn_var, out);
}

// Round 6
// 229.995 us; speedup vs baseline: 1.4914x; 1.0431x over previous
//
#include <hip/hip_runtime.h>
#include <math.h>

typedef __bf16  bf16x8 __attribute__((ext_vector_type(8)));
typedef float   f32x4  __attribute__((ext_vector_type(4)));

// async global->LDS, 16B per lane. Pass per-lane dest (= base + lane*16).
#define GLD_LDS16(dst, src)                                                      \
    __builtin_amdgcn_global_load_lds(                                            \
        (const __attribute__((address_space(1))) unsigned int*)(src),            \
        (__attribute__((address_space(3))) unsigned int*)(dst), 16, 0, 0)

// ---------------------------------------------------------------------------
// Kernel T v4: x[b,ci,h,w] fp32 -> xT[b,h,w,ci] bf16 + fused pool partials.
// MLP fix: ALL 16 float4 loads issued into registers BEFORE any LDS write
// (two separate loops) -> 16 vmem insts in flight per wave, instead of
// latency-exposed load->ds_write pairs. Everything else identical to v3.
// ---------------------------------------------------------------------------
__global__ __launch_bounds__(256) void transpose_kernel(const float* __restrict__ x,
                                                        __bf16* __restrict__ xT,
                                                        float* __restrict__ psum) {
    __shared__ unsigned int lp[128][68];   // [ci-pair][w], pad 64->68
    const int h = blockIdx.x, b = blockIdx.y;
    const int t = threadIdx.x;
    const int w4 = t & 15;                 // float4 group in w
    // phase L0: issue ALL loads first (ILP: 16 outstanding vmem per thread)
    float4 va[8], vc[8];
#pragma unroll
    for (int k = 0; k < 8; ++k) {
        int ci2 = k * 16 + (t >> 4);       // 0..127
        int ci  = ci2 * 2;
        va[k] = *(const float4*)(x + (((size_t)(b * 256 + ci    ) * 64 + h) * 64 + w4 * 4));
        vc[k] = *(const float4*)(x + (((size_t)(b * 256 + ci + 1) * 64 + h) * 64 + w4 * 4));
    }
    // phase L1: convert + LDS write + pool partial sums
    float psA[8], psC[8];
#pragma unroll
    for (int k = 0; k < 8; ++k) {
        int ci2 = k * 16 + (t >> 4);
        const float4 a = va[k], c = vc[k];
        psA[k] = a.x + a.y + a.z + a.w;
        psC[k] = c.x + c.y + c.z + c.w;
        union { __bf16 hh[2]; unsigned int u; } p0, p1, p2, p3;
        p0.hh[0] = (__bf16)a.x; p0.hh[1] = (__bf16)c.x;
        p1.hh[0] = (__bf16)a.y; p1.hh[1] = (__bf16)c.y;
        p2.hh[0] = (__bf16)a.z; p2.hh[1] = (__bf16)c.z;
        p3.hh[0] = (__bf16)a.w; p3.hh[1] = (__bf16)c.w;
        uint4 v = {p0.u, p1.u, p2.u, p3.u};
        *(uint4*)&lp[ci2][w4 * 4] = v;
    }
    // fused pool partials: reduce across the 16 w4-lanes of each group
#pragma unroll
    for (int k = 0; k < 8; ++k) {
        float sA = psA[k], sC = psC[k];
#pragma unroll
        for (int m = 1; m <= 8; m <<= 1) {
            sA += __shfl_xor(sA, m, 64);
            sC += __shfl_xor(sC, m, 64);
        }
        if (w4 == 0) {
            int ci2 = k * 16 + (t >> 4);
            *(float2*)&psum[(((size_t)b * 64 + h) * 256) + ci2 * 2] =
                make_float2(sA, sC);
        }
    }
    __syncthreads();
    // phase S: thread (w, q) writes ci [64q, 64q+64) at fixed w -> 8 x 16B
    const int w = t >> 2, q = t & 3;
    __bf16* dst = xT + (((size_t)b * 64 + h) * 64 + w) * 256 + q * 64;
#pragma unroll
    for (int j = 0; j < 8; ++j) {
        int c0 = q * 32 + j * 4;
        uint4 v;
        v.x = lp[c0 + 0][w];
        v.y = lp[c0 + 1][w];
        v.z = lp[c0 + 2][w];
        v.w = lp[c0 + 3][w];
        *(uint4*)(dst + j * 8) = v;        // wave: 64 lanes = 8KB contiguous
    }
}

// ---------------------------------------------------------------------------
// Kernel R v2: one block per b (16 blocks x 256 thr).
// 1) pooled_b[ci] = sum_h psum[b][h][ci] / 4096   (coalesced over ci)
// 2) zl/zt[n] via LDS + half-wave shuffle reduce
// 3) 4 threads compute lambda*R -> slg[b][n][p][12]
// ---------------------------------------------------------------------------
__global__ __launch_bounds__(256) void routing_kernel(
    const float* __restrict__ psum, const float* __restrict__ w_lambda,
    const float* __restrict__ w_theta, float* __restrict__ slg) {
    const int b = blockIdx.x, t = threadIdx.x;
    float s = 0.f;
    const float* p = psum + (size_t)b * 16384 + t;
#pragma unroll 8
    for (int h = 0; h < 64; ++h) s += p[h * 256];
    const float pv = s * (1.f / 4096.f);
    __shared__ float red[8][256];
    float4 wl = *(const float4*)&w_lambda[t * 4];
    float4 wt = *(const float4*)&w_theta[t * 4];
    red[0][t] = pv * wl.x; red[1][t] = pv * wl.y;
    red[2][t] = pv * wl.z; red[3][t] = pv * wl.w;
    red[4][t] = pv * wt.x; red[5][t] = pv * wt.y;
    red[6][t] = pv * wt.z; red[7][t] = pv * wt.w;
    __syncthreads();
    __shared__ float zv[8];
    const int rrow = t >> 5, i = t & 31;   // 8 rows x 32 threads
    float acc = red[rrow][i]       + red[rrow][i + 32]
              + red[rrow][i + 64]  + red[rrow][i + 96]
              + red[rrow][i + 128] + red[rrow][i + 160]
              + red[rrow][i + 192] + red[rrow][i + 224];
#pragma unroll
    for (int m = 16; m >= 1; m >>= 1) acc += __shfl_xor(acc, m, 64);
    if (i == 0) zv[rrow] = acc;
    __syncthreads();
    if (t < 4) {
        const int n = t;
        float zl = zv[n], zt = zv[4 + n];
        float lam = 1.f / (1.f + expf(-zl));
        float th  = 3.14159265358979323846f * (zt / (1.f + fabsf(zt)));
        float xc = cosf(th), ys = sinf(th);
        float a = xc - ys, bb = xc * ys, c = xc + ys;
        float R[9][9];
#pragma unroll
        for (int ii = 0; ii < 9; ii++)
#pragma unroll
            for (int jj = 0; jj < 9; jj++) R[ii][jj] = 0.f;
        if (th >= 0.f) {
            R[0][0] = a;       R[0][1] = 1 - a;
            R[1][1] = xc - bb; R[1][2] = bb;       R[1][4] = 1 - c + bb; R[1][5] = ys - bb;
            R[2][2] = a;       R[2][5] = 1 - a;
            R[3][0] = bb;      R[3][1] = ys - bb;  R[3][3] = xc - bb;    R[3][4] = 1 - c + bb;
            R[4][4] = 1.f;
            R[5][4] = 1 - c + bb; R[5][5] = xc - bb; R[5][7] = ys - bb;  R[5][8] = bb;
            R[6][3] = 1 - a;   R[6][6] = a;
            R[7][3] = ys - bb; R[7][4] = 1 - c + bb; R[7][6] = bb;       R[7][7] = xc - bb;
            R[8][7] = 1 - a;   R[8][8] = a;
        } else {
            R[0][0] = c;       R[0][3] = 1 - c;
            R[1][0] = -bb;     R[1][1] = xc + bb;  R[1][3] = bb - ys;    R[1][4] = 1 - a - bb;
            R[2][1] = 1 - c;   R[2][2] = c;
            R[3][3] = xc + bb; R[3][4] = 1 - a - bb; R[3][6] = -bb;      R[3][7] = bb - ys;
            R[4][4] = 1.f;
            R[5][1] = bb - ys; R[5][2] = -bb;      R[5][4] = 1 - a - bb; R[5][5] = xc + bb;
            R[6][6] = c;       R[6][7] = 1 - c;
            R[7][4] = 1 - a - bb; R[7][5] = bb - ys; R[7][7] = xc + bb;  R[7][8] = -bb;
            R[8][5] = 1 - c;   R[8][8] = c;
        }
        float* o = slg + ((size_t)(b * 4 + n) * 9) * 12;
#pragma unroll
        for (int pp = 0; pp < 9; pp++) {
#pragma unroll
            for (int q = 0; q < 9; q++) o[pp * 12 + q] = lam * R[pp][q];
            o[pp * 12 + 9] = o[pp * 12 + 10] = o[pp * 12 + 11] = 0.f;
        }
    }
}

// ---------------------------------------------------------------------------
// Kernel C v3: rotated weights. rwq[b][tap][co][ci] bf16.
// MLP fix: grid 1024 (co x ci-quarter) instead of 256 -> 4 blocks/CU,
// 16 waves/CU (was 1 wave/SIMD). Thread = (ci_local 0..63, b-group 0..3);
// each thread does 4 b x 9 p. Weight traffic unchanged (no duplication).
// ---------------------------------------------------------------------------
__global__ __launch_bounds__(256) void rotw_kernel(
    const float* __restrict__ weight, const float* __restrict__ slg,
    __bf16* __restrict__ rwq) {
    __shared__ __attribute__((aligned(16))) float sl[16][4][9][12];
    const int lin = blockIdx.x;
    const int co  = lin >> 2;
    const int ciq = lin & 3;
    const int t   = threadIdx.x;
    const int ci  = ciq * 64 + (t & 63);
    const int bg  = t >> 6;               // 0..3
    for (int i = t; i < 1728; i += 256)    // 6912 floats = 1728 float4
        ((float4*)sl)[i] = ((const float4*)slg)[i];
    float4 wa[4], wb[4];
    float  wc[4];
#pragma unroll
    for (int n = 0; n < 4; n++) {
        const float* wp = weight + ((size_t)n * 256 + co) * 2304 + (size_t)ci * 9;
        wa[n] = make_float4(wp[0], wp[1], wp[2], wp[3]);
        wb[n] = make_float4(wp[4], wp[5], wp[6], wp[7]);
        wc[n] = wp[8];
    }
    __syncthreads();
#pragma unroll
    for (int bo = 0; bo < 4; bo++) {
        const int b = bg * 4 + bo;
#pragma unroll
        for (int p = 0; p < 9; p++) {
            float s = 0.f;
#pragma unroll
            for (int n = 0; n < 4; n++) {
                float4 sa = *(const float4*)&sl[b][n][p][0];
                float4 sb = *(const float4*)&sl[b][n][p][4];
                float  sc = sl[b][n][p][8];
                s += sa.x * wa[n].x + sa.y * wa[n].y + sa.z * wa[n].z + sa.w * wa[n].w
                   + sb.x * wb[n].x + sb.y * wb[n].y + sb.z * wb[n].z + sb.w * wb[n].w
                   + sc * wc[n];
            }
            rwq[(((size_t)b * 9 + p) * 256 + co) * 256 + ci] = (__bf16)s;
        }
    }
}

// ---------------------------------------------------------------------------
// Kernel D: implicit-GEMM conv + fused BN/ReLU — VERBATIM R0 (83.5us proven).
// 2 blocks/CU co-resident (8 waves/CU) provides the overlap; R2/R3 showed
// explicit double-buffering at 1 blk/CU loses the TLP and regresses.
// ---------------------------------------------------------------------------
__global__ __launch_bounds__(256, 2) void conv_kernel(
    const __bf16* __restrict__ xT, const __bf16* __restrict__ rwq,
    const float* __restrict__ bn_gamma, const float* __restrict__ bn_beta,
    const float* __restrict__ bn_mean,  const float* __restrict__ bn_var,
    float* __restrict__ out) {
    __shared__ __attribute__((aligned(16))) __bf16 xs[10][4][66][8];
    __shared__ __attribute__((aligned(16))) __bf16 as9[9][4][66][8];
    __shared__ float bns[64], bnh[64];

    const int t    = threadIdx.x;
    const int lane = t & 63;
    const int wv   = t >> 6;
    const int l15  = lane & 15;
    const int kq4  = lane >> 4;

    const int lin  = blockIdx.x;
    const int r    = lin & 7;
    const int k    = lin >> 3;
    const int b    = (r << 1) | (k >> 5);
    const int inner = k & 31;
    const int co0  = (inner & 3) << 6;
    const int h0   = (inner >> 2) << 3;

    if (t < 64) {
        float inv = rsqrtf(bn_var[co0 + t] + 1e-5f);
        float sc = bn_gamma[co0 + t] * inv;
        bns[t] = sc;
        bnh[t] = bn_beta[co0 + t] - bn_mean[co0 + t] * sc;
    }

    f32x4 acc[2][4][4];
#pragma unroll
    for (int rr = 0; rr < 2; rr++)
#pragma unroll
        for (int m = 0; m < 4; m++)
#pragma unroll
            for (int n = 0; n < 4; n++) acc[rr][m][n] = (f32x4){0.f, 0.f, 0.f, 0.f};

    const uint4 zero4 = {0u, 0u, 0u, 0u};
    if (t < 40) {
        int rr = t >> 2, kq = t & 3;
        *(uint4*)&xs[rr][kq][0][0]  = zero4;
        *(uint4*)&xs[rr][kq][65][0] = zero4;
    }

    for (int ci0 = 0; ci0 < 256; ci0 += 32) {
        __syncthreads();                 // prev chunk's compute done before overwrite
#pragma unroll
        for (int u = wv * 10; u < wv * 10 + 10; u++) {
            int rr = u >> 2, kq = u & 3;
            int hh = h0 - 1 + rr;
            if (hh >= 0 && hh < 64) {
                const __bf16* src = xT + (((size_t)(b * 64 + hh) * 64 + lane) * 256 + ci0 + kq * 8);
                GLD_LDS16(&xs[rr][kq][1 + lane][0], src);
            } else {
                *(uint4*)&xs[rr][kq][1 + lane][0] = zero4;
            }
        }
#pragma unroll
        for (int u = wv * 9; u < wv * 9 + 9; u++) {
            int tap = u >> 2, kq = u & 3;
            const __bf16* src = rwq +
                ((((size_t)b * 9 + tap) * 256 + co0 + lane) * 256 + ci0 + kq * 8);
            GLD_LDS16(&as9[tap][kq][lane][0], src);
        }
        __syncthreads();                 // drains DMA; xs + as9 ready
#pragma unroll
        for (int tap = 0; tap < 9; tap++) {
            const int dh = tap / 3, dw = tap % 3;
            bf16x8 af[4];
#pragma unroll
            for (int m = 0; m < 4; m++)
                af[m] = *(const bf16x8*)&as9[tap][kq4][m * 16 + l15][0];
#pragma unroll
            for (int rr = 0; rr < 2; rr++) {
                const int hl = wv + rr * 4;
#pragma unroll
                for (int nt = 0; nt < 4; nt++) {
                    bf16x8 bfr = *(const bf16x8*)&xs[hl + dh][kq4][nt * 16 + l15 + dw][0];
#pragma unroll
                    for (int m = 0; m < 4; m++)
                        acc[rr][m][nt] = __builtin_amdgcn_mfma_f32_16x16x32_bf16(
                            af[m], bfr, acc[rr][m][nt], 0, 0, 0);
                }
            }
        }
    }

    // epilogue: BN + ReLU. D layout: row(co) = kq4*4+reg, col(w) = l15
#pragma unroll
    for (int rr = 0; rr < 2; rr++) {
        const int h = h0 + wv + rr * 4;
#pragma unroll
        for (int m = 0; m < 4; m++) {
#pragma unroll
            for (int reg = 0; reg < 4; reg++) {
                int col = m * 16 + kq4 * 4 + reg;        // local co 0..63
                float sc = bns[col], sh = bnh[col];
                int co = co0 + col;
#pragma unroll
                for (int nt = 0; nt < 4; nt++) {
                    int w = nt * 16 + l15;
                    float v = acc[rr][m][nt][reg] * sc + sh;
                    out[(((size_t)b * 256 + co) * 64 + h) * 64 + w] = v > 0.f ? v : 0.f;
                }
            }
        }
    }
}

// ---------------------------------------------------------------------------
extern "C" void kernel_launch(void* const* d_in, const int* in_sizes, int n_in,
                              void* d_out, int out_size, void* d_ws, size_t ws_size,
                              hipStream_t stream) {
    const float* x        = (const float*)d_in[0];
    const float* weight   = (const float*)d_in[1];
    const float* w_lambda = (const float*)d_in[2];
    const float* w_theta  = (const float*)d_in[3];
    const float* bn_gamma = (const float*)d_in[4];
    const float* bn_beta  = (const float*)d_in[5];
    const float* bn_mean  = (const float*)d_in[6];
    const float* bn_var   = (const float*)d_in[7];
    float* out = (float*)d_out;

    char* ws = (char*)d_ws;
    float*  slg     = (float*)(ws + 16384);             // 27.6KB (16*4*9*12 f)
    __bf16* xT      = (__bf16*)(ws + 49152);            // 33.5 MB
    __bf16* rwq     = (__bf16*)(ws + 49152 + 33554432); // 18.9 MB
    float*  psum    = out;   // 4MB scratch in d_out; conv overwrites it later

    transpose_kernel<<<dim3(64, 16), 256, 0, stream>>>(x, xT, psum);
    routing_kernel<<<16, 256, 0, stream>>>(psum, w_lambda, w_theta, slg);
    rotw_kernel<<<1024, 256, 0, stream>>>(weight, slg, rwq);
    conv_kernel<<<512, 256, 0, stream>>>(xT, rwq,
                                         bn_gamma, bn_beta, bn_mean, bn_var, out);
}

// Round 7
// 229.060 us; speedup vs baseline: 1.4975x; 1.0041x over previous
//
#include <hip/hip_runtime.h>
#include <math.h>

typedef __bf16  bf16x8 __attribute__((ext_vector_type(8)));
typedef float   f32x4  __attribute__((ext_vector_type(4)));

// async global->LDS, 16B per lane. Pass per-lane dest (= base + lane*16).
#define GLD_LDS16(dst, src)                                                      \
    __builtin_amdgcn_global_load_lds(                                            \
        (const __attribute__((address_space(1))) unsigned int*)(src),            \
        (__attribute__((address_space(3))) unsigned int*)(dst), 16, 0, 0)

// ---------------------------------------------------------------------------
// Kernel T v5: x[b,ci,h,w] fp32 -> xT[b,h,w,ci] bf16 + fused pool partials.
// DRAM-granule fix: old tiling read 256B segments at 16KB stride (~1 TB/s
// DRAM-page-thrash cap; the R6 ILP hoist changed nothing => not latency).
// New tile: block = (b, ci-half, h-quad). Per wave-instr the 64 lanes read
// x[b, ci, h0:h0+4, 0:64] = 1KB CONTIGUOUS (h=lane>>4, w4=lane&15).
// LDS lp[pair][h][68] holds packed ci-pair u32; phase-S reads are 16-lane
// same-word broadcasts (conflict-free) and writes 256B-contiguous groups.
// Pool partials: 4 shfl_xor levels -> psum[b][hq*4+h][ci] (same [b][64][256]
// layout routing v2 already consumes; no atomics, no zero-init).
// ---------------------------------------------------------------------------
__global__ __launch_bounds__(256, 2) void transpose_kernel(const float* __restrict__ x,
                                                           __bf16* __restrict__ xT,
                                                           float* __restrict__ psum) {
    __shared__ unsigned int lp[64][4][68];   // [ci-pair][h][w pad 64->68]
    const int bx = blockIdx.x;               // 0..31
    const int b  = blockIdx.y;               // 0..15
    const int hq = bx >> 1, ch = bx & 1;
    const int h0 = hq * 4;
    const int t    = threadIdx.x;
    const int lane = t & 63, wv = t >> 6;
    const int hl = lane >> 4;                // 0..3
    const int w4 = lane & 15;                // 0..15

    // phase L0: issue all 32 global loads (wave reads 1KB contiguous each)
    float4 va[16], vc[16];
    const float* xb = x + (((size_t)(b * 256 + ch * 128) * 64) + (h0 + hl)) * 64 + w4 * 4;
#pragma unroll
    for (int k = 0; k < 16; ++k) {
        const int p = k * 4 + wv;            // ci-pair 0..63 (wave-uniform)
        va[k] = *(const float4*)(xb + (size_t)(2 * p)     * 4096);
        vc[k] = *(const float4*)(xb + (size_t)(2 * p + 1) * 4096);
    }
    // phase L1: pack to LDS + pool partials
#pragma unroll
    for (int k = 0; k < 16; ++k) {
        const int p = k * 4 + wv;
        const float4 a = va[k], c = vc[k];
        union { __bf16 hh[2]; unsigned int u; } p0, p1, p2, p3;
        p0.hh[0] = (__bf16)a.x; p0.hh[1] = (__bf16)c.x;
        p1.hh[0] = (__bf16)a.y; p1.hh[1] = (__bf16)c.y;
        p2.hh[0] = (__bf16)a.z; p2.hh[1] = (__bf16)c.z;
        p3.hh[0] = (__bf16)a.w; p3.hh[1] = (__bf16)c.w;
        uint4 v = {p0.u, p1.u, p2.u, p3.u};
        *(uint4*)&lp[p][hl][w4 * 4] = v;
        float sA = a.x + a.y + a.z + a.w;
        float sC = c.x + c.y + c.z + c.w;
#pragma unroll
        for (int m = 1; m <= 8; m <<= 1) {   // reduce across the 16 w4 lanes
            sA += __shfl_xor(sA, m, 64);
            sC += __shfl_xor(sC, m, 64);
        }
        if (w4 == 0) {
            *(float2*)&psum[(((size_t)b * 64) + hq * 4 + hl) * 256 + ch * 128 + 2 * p] =
                make_float2(sA, sC);
        }
    }
    __syncthreads();
    // phase S: 16B chunk per thread per iter; 16 lanes share one (h,w) pos
    // (LDS same-word broadcast); global writes 256B contiguous per group.
#pragma unroll
    for (int j = 0; j < 16; ++j) {
        const int cid = j * 256 + t;
        const int pos = cid >> 4;            // 0..255 : h(2b) x w(6b)
        const int p0  = (cid & 15) * 4;      // pair base 0..60
        const int hh = pos >> 6, w = pos & 63;
        uint4 v;
        v.x = lp[p0 + 0][hh][w];
        v.y = lp[p0 + 1][hh][w];
        v.z = lp[p0 + 2][hh][w];
        v.w = lp[p0 + 3][hh][w];
        *(uint4*)(xT + (((size_t)(b * 64 + h0 + hh) * 64 + w) * 256) + ch * 128 + p0 * 2) = v;
    }
}

// ---------------------------------------------------------------------------
// Kernel R v2: one block per b (16 blocks x 256 thr).
// 1) pooled_b[ci] = sum_slot psum[b][slot][ci] / 4096   (coalesced over ci)
// 2) zl/zt[n] via LDS + half-wave shuffle reduce
// 3) 4 threads compute lambda*R -> slg[b][n][p][12]
// ---------------------------------------------------------------------------
__global__ __launch_bounds__(256) void routing_kernel(
    const float* __restrict__ psum, const float* __restrict__ w_lambda,
    const float* __restrict__ w_theta, float* __restrict__ slg) {
    const int b = blockIdx.x, t = threadIdx.x;
    float s = 0.f;
    const float* p = psum + (size_t)b * 16384 + t;
#pragma unroll 8
    for (int h = 0; h < 64; ++h) s += p[h * 256];
    const float pv = s * (1.f / 4096.f);
    __shared__ float red[8][256];
    float4 wl = *(const float4*)&w_lambda[t * 4];
    float4 wt = *(const float4*)&w_theta[t * 4];
    red[0][t] = pv * wl.x; red[1][t] = pv * wl.y;
    red[2][t] = pv * wl.z; red[3][t] = pv * wl.w;
    red[4][t] = pv * wt.x; red[5][t] = pv * wt.y;
    red[6][t] = pv * wt.z; red[7][t] = pv * wt.w;
    __syncthreads();
    __shared__ float zv[8];
    const int rrow = t >> 5, i = t & 31;   // 8 rows x 32 threads
    float acc = red[rrow][i]       + red[rrow][i + 32]
              + red[rrow][i + 64]  + red[rrow][i + 96]
              + red[rrow][i + 128] + red[rrow][i + 160]
              + red[rrow][i + 192] + red[rrow][i + 224];
#pragma unroll
    for (int m = 16; m >= 1; m >>= 1) acc += __shfl_xor(acc, m, 64);
    if (i == 0) zv[rrow] = acc;
    __syncthreads();
    if (t < 4) {
        const int n = t;
        float zl = zv[n], zt = zv[4 + n];
        float lam = 1.f / (1.f + expf(-zl));
        float th  = 3.14159265358979323846f * (zt / (1.f + fabsf(zt)));
        float xc = cosf(th), ys = sinf(th);
        float a = xc - ys, bb = xc * ys, c = xc + ys;
        float R[9][9];
#pragma unroll
        for (int ii = 0; ii < 9; ii++)
#pragma unroll
            for (int jj = 0; jj < 9; jj++) R[ii][jj] = 0.f;
        if (th >= 0.f) {
            R[0][0] = a;       R[0][1] = 1 - a;
            R[1][1] = xc - bb; R[1][2] = bb;       R[1][4] = 1 - c + bb; R[1][5] = ys - bb;
            R[2][2] = a;       R[2][5] = 1 - a;
            R[3][0] = bb;      R[3][1] = ys - bb;  R[3][3] = xc - bb;    R[3][4] = 1 - c + bb;
            R[4][4] = 1.f;
            R[5][4] = 1 - c + bb; R[5][5] = xc - bb; R[5][7] = ys - bb;  R[5][8] = bb;
            R[6][3] = 1 - a;   R[6][6] = a;
            R[7][3] = ys - bb; R[7][4] = 1 - c + bb; R[7][6] = bb;       R[7][7] = xc - bb;
            R[8][7] = 1 - a;   R[8][8] = a;
        } else {
            R[0][0] = c;       R[0][3] = 1 - c;
            R[1][0] = -bb;     R[1][1] = xc + bb;  R[1][3] = bb - ys;    R[1][4] = 1 - a - bb;
            R[2][1] = 1 - c;   R[2][2] = c;
            R[3][3] = xc + bb; R[3][4] = 1 - a - bb; R[3][6] = -bb;      R[3][7] = bb - ys;
            R[4][4] = 1.f;
            R[5][1] = bb - ys; R[5][2] = -bb;      R[5][4] = 1 - a - bb; R[5][5] = xc + bb;
            R[6][6] = c;       R[6][7] = 1 - c;
            R[7][4] = 1 - a - bb; R[7][5] = bb - ys; R[7][7] = xc + bb;  R[7][8] = -bb;
            R[8][5] = 1 - c;   R[8][8] = c;
        }
        float* o = slg + ((size_t)(b * 4 + n) * 9) * 12;
#pragma unroll
        for (int pp = 0; pp < 9; pp++) {
#pragma unroll
            for (int q = 0; q < 9; q++) o[pp * 12 + q] = lam * R[pp][q];
            o[pp * 12 + 9] = o[pp * 12 + 10] = o[pp * 12 + 11] = 0.f;
        }
    }
}

// ---------------------------------------------------------------------------
// Kernel C v3: rotated weights. rwq[b][tap][co][ci] bf16.
// Grid 1024 (co x ci-quarter) -> 4 blocks/CU, 16 waves/CU.
// Thread = (ci_local 0..63, b-group 0..3); each does 4 b x 9 p.
// ---------------------------------------------------------------------------
__global__ __launch_bounds__(256) void rotw_kernel(
    const float* __restrict__ weight, const float* __restrict__ slg,
    __bf16* __restrict__ rwq) {
    __shared__ __attribute__((aligned(16))) float sl[16][4][9][12];
    const int lin = blockIdx.x;
    const int co  = lin >> 2;
    const int ciq = lin & 3;
    const int t   = threadIdx.x;
    const int ci  = ciq * 64 + (t & 63);
    const int bg  = t >> 6;               // 0..3
    for (int i = t; i < 1728; i += 256)    // 6912 floats = 1728 float4
        ((float4*)sl)[i] = ((const float4*)slg)[i];
    float4 wa[4], wb[4];
    float  wc[4];
#pragma unroll
    for (int n = 0; n < 4; n++) {
        const float* wp = weight + ((size_t)n * 256 + co) * 2304 + (size_t)ci * 9;
        wa[n] = make_float4(wp[0], wp[1], wp[2], wp[3]);
        wb[n] = make_float4(wp[4], wp[5], wp[6], wp[7]);
        wc[n] = wp[8];
    }
    __syncthreads();
#pragma unroll
    for (int bo = 0; bo < 4; bo++) {
        const int b = bg * 4 + bo;
#pragma unroll
        for (int p = 0; p < 9; p++) {
            float s = 0.f;
#pragma unroll
            for (int n = 0; n < 4; n++) {
                float4 sa = *(const float4*)&sl[b][n][p][0];
                float4 sb = *(const float4*)&sl[b][n][p][4];
                float  sc = sl[b][n][p][8];
                s += sa.x * wa[n].x + sa.y * wa[n].y + sa.z * wa[n].z + sa.w * wa[n].w
                   + sb.x * wb[n].x + sb.y * wb[n].y + sb.z * wb[n].z + sb.w * wb[n].w
                   + sc * wc[n];
            }
            rwq[(((size_t)b * 9 + p) * 256 + co) * 256 + ci] = (__bf16)s;
        }
    }
}

// ---------------------------------------------------------------------------
// Kernel D: implicit-GEMM conv + fused BN/ReLU — VERBATIM R0 (83.5us proven).
// 2 blocks/CU co-resident (8 waves/CU) provides the overlap; R2/R3 showed
// explicit double-buffering at 1 blk/CU loses the TLP and regresses.
// ---------------------------------------------------------------------------
__global__ __launch_bounds__(256, 2) void conv_kernel(
    const __bf16* __restrict__ xT, const __bf16* __restrict__ rwq,
    const float* __restrict__ bn_gamma, const float* __restrict__ bn_beta,
    const float* __restrict__ bn_mean,  const float* __restrict__ bn_var,
    float* __restrict__ out) {
    __shared__ __attribute__((aligned(16))) __bf16 xs[10][4][66][8];
    __shared__ __attribute__((aligned(16))) __bf16 as9[9][4][66][8];
    __shared__ float bns[64], bnh[64];

    const int t    = threadIdx.x;
    const int lane = t & 63;
    const int wv   = t >> 6;
    const int l15  = lane & 15;
    const int kq4  = lane >> 4;

    const int lin  = blockIdx.x;
    const int r    = lin & 7;
    const int k    = lin >> 3;
    const int b    = (r << 1) | (k >> 5);
    const int inner = k & 31;
    const int co0  = (inner & 3) << 6;
    const int h0   = (inner >> 2) << 3;

    if (t < 64) {
        float inv = rsqrtf(bn_var[co0 + t] + 1e-5f);
        float sc = bn_gamma[co0 + t] * inv;
        bns[t] = sc;
        bnh[t] = bn_beta[co0 + t] - bn_mean[co0 + t] * sc;
    }

    f32x4 acc[2][4][4];
#pragma unroll
    for (int rr = 0; rr < 2; rr++)
#pragma unroll
        for (int m = 0; m < 4; m++)
#pragma unroll
            for (int n = 0; n < 4; n++) acc[rr][m][n] = (f32x4){0.f, 0.f, 0.f, 0.f};

    const uint4 zero4 = {0u, 0u, 0u, 0u};
    if (t < 40) {
        int rr = t >> 2, kq = t & 3;
        *(uint4*)&xs[rr][kq][0][0]  = zero4;
        *(uint4*)&xs[rr][kq][65][0] = zero4;
    }

    for (int ci0 = 0; ci0 < 256; ci0 += 32) {
        __syncthreads();                 // prev chunk's compute done before overwrite
#pragma unroll
        for (int u = wv * 10; u < wv * 10 + 10; u++) {
            int rr = u >> 2, kq = u & 3;
            int hh = h0 - 1 + rr;
            if (hh >= 0 && hh < 64) {
                const __bf16* src = xT + (((size_t)(b * 64 + hh) * 64 + lane) * 256 + ci0 + kq * 8);
                GLD_LDS16(&xs[rr][kq][1 + lane][0], src);
            } else {
                *(uint4*)&xs[rr][kq][1 + lane][0] = zero4;
            }
        }
#pragma unroll
        for (int u = wv * 9; u < wv * 9 + 9; u++) {
            int tap = u >> 2, kq = u & 3;
            const __bf16* src = rwq +
                ((((size_t)b * 9 + tap) * 256 + co0 + lane) * 256 + ci0 + kq * 8);
            GLD_LDS16(&as9[tap][kq][lane][0], src);
        }
        __syncthreads();                 // drains DMA; xs + as9 ready
#pragma unroll
        for (int tap = 0; tap < 9; tap++) {
            const int dh = tap / 3, dw = tap % 3;
            bf16x8 af[4];
#pragma unroll
            for (int m = 0; m < 4; m++)
                af[m] = *(const bf16x8*)&as9[tap][kq4][m * 16 + l15][0];
#pragma unroll
            for (int rr = 0; rr < 2; rr++) {
                const int hl = wv + rr * 4;
#pragma unroll
                for (int nt = 0; nt < 4; nt++) {
                    bf16x8 bfr = *(const bf16x8*)&xs[hl + dh][kq4][nt * 16 + l15 + dw][0];
#pragma unroll
                    for (int m = 0; m < 4; m++)
                        acc[rr][m][nt] = __builtin_amdgcn_mfma_f32_16x16x32_bf16(
                            af[m], bfr, acc[rr][m][nt], 0, 0, 0);
                }
            }
        }
    }

    // epilogue: BN + ReLU. D layout: row(co) = kq4*4+reg, col(w) = l15
#pragma unroll
    for (int rr = 0; rr < 2; rr++) {
        const int h = h0 + wv + rr * 4;
#pragma unroll
        for (int m = 0; m < 4; m++) {
#pragma unroll
            for (int reg = 0; reg < 4; reg++) {
                int col = m * 16 + kq4 * 4 + reg;        // local co 0..63
                float sc = bns[col], sh = bnh[col];
                int co = co0 + col;
#pragma unroll
                for (int nt = 0; nt < 4; nt++) {
                    int w = nt * 16 + l15;
                    float v = acc[rr][m][nt][reg] * sc + sh;
                    out[(((size_t)b * 256 + co) * 64 + h) * 64 + w] = v > 0.f ? v : 0.f;
                }
            }
        }
    }
}

// ---------------------------------------------------------------------------
extern "C" void kernel_launch(void* const* d_in, const int* in_sizes, int n_in,
                              void* d_out, int out_size, void* d_ws, size_t ws_size,
                              hipStream_t stream) {
    const float* x        = (const float*)d_in[0];
    const float* weight   = (const float*)d_in[1];
    const float* w_lambda = (const float*)d_in[2];
    const float* w_theta  = (const float*)d_in[3];
    const float* bn_gamma = (const float*)d_in[4];
    const float* bn_beta  = (const float*)d_in[5];
    const float* bn_mean  = (const float*)d_in[6];
    const float* bn_var   = (const float*)d_in[7];
    float* out = (float*)d_out;

    char* ws = (char*)d_ws;
    float*  slg     = (float*)(ws + 16384);             // 27.6KB (16*4*9*12 f)
    __bf16* xT      = (__bf16*)(ws + 49152);            // 33.5 MB
    __bf16* rwq     = (__bf16*)(ws + 49152 + 33554432); // 18.9 MB
    float*  psum    = out;   // 1MB scratch in d_out; conv overwrites it later

    transpose_kernel<<<dim3(32, 16), 256, 0, stream>>>(x, xT, psum);
    routing_kernel<<<16, 256, 0, stream>>>(psum, w_lambda, w_theta, slg);
    rotw_kernel<<<1024, 256, 0, stream>>>(weight, slg, rwq);
    conv_kernel<<<512, 256, 0, stream>>>(xT, rwq,
                                         bn_gamma, bn_beta, bn_mean, bn_var, out);
}